// Round 1
// baseline (235.928 us; speedup 1.0000x reference)
//
#include <hip/hip_runtime.h>
#include <hip/hip_bf16.h>

#define NH   16
#define HD   64
#define HID  1024
#define TSEQ 2048
#define BATCH 2
#define KSCALE 0.18033688011112042f   // 0.125 * log2(e), folded into Wk/bk

typedef __attribute__((ext_vector_type(4))) float f32x4;
typedef __attribute__((ext_vector_type(8))) short s16x8;
typedef __attribute__((ext_vector_type(4))) short s16x4;
typedef __attribute__((ext_vector_type(8))) _Float16 f16x8;
typedef __attribute__((ext_vector_type(4))) _Float16 f16x4;
typedef __attribute__((ext_vector_type(2))) _Float16 f16x2;

__device__ __forceinline__ unsigned short f2bf(float f) {
  union { float f; unsigned int u; } v; v.f = f;
  unsigned int r = v.u + 0x7fffu + ((v.u >> 16) & 1u);
  return (unsigned short)(r >> 16);
}
__device__ __forceinline__ float bf2f(unsigned short b) {
  union { unsigned int u; float f; } v; v.u = ((unsigned int)b) << 16; return v.f;
}

// async global->LDS, 16B per lane; LDS dest must be wave-uniform base (+lane*16 by HW)
__device__ __forceinline__ void gll16(const void* g, void* l) {
  __builtin_amdgcn_global_load_lds(
      (const __attribute__((address_space(1))) unsigned int*)g,
      (__attribute__((address_space(3))) unsigned int*)l, 16, 0, 0);
}

// ---------------- one cast kernel: h + all 4 weights (Wk pre-scaled) ----------------
__global__ __launch_bounds__(256) void cast_all_k(
    const float* __restrict__ h,
    const float* __restrict__ w0, const float* __restrict__ w1,
    const float* __restrict__ w2, const float* __restrict__ w3,
    unsigned short* __restrict__ hb, unsigned short* __restrict__ wbase) {
  int i = blockIdx.x * 256 + threadIdx.x;  // 2097152 float4 total
  const float* src; unsigned short* dst; int idx; float sc = 1.f;
  if (i < 1048576) { src = h; dst = hb; idx = i; }
  else {
    int idx4 = i - 1048576;
    int w = idx4 >> 18;
    idx = idx4 & 262143;
    src = (w == 0) ? w0 : (w == 1) ? w1 : (w == 2) ? w2 : w3;
    dst = wbase + (size_t)(idx4 - idx) * 4;   // contiguous weight region
    if (w == 1) sc = KSCALE;
  }
  float4 v = ((const float4*)src)[idx];
  ushort4 o;
  o.x = f2bf(v.x * sc); o.y = f2bf(v.y * sc); o.z = f2bf(v.z * sc); o.w = f2bf(v.w * sc);
  ((ushort4*)dst)[idx] = o;
}

// ---------------- Fused QKV projection: one 4096x3072x1024 NT-GEMM ----------------
// m97 structure: 128x128 tile, BK=32, global_load_lds dwordx4 staging,
// double-buffered LDS, prefetch issued before compute (latency hides under MFMA).
__global__ __launch_bounds__(256) void gemm_qkv(
    const unsigned short* __restrict__ hb,
    const unsigned short* __restrict__ wcat,   // [3072][1024] = Wq|Wk|Wv, Wk pre-scaled
    const float* __restrict__ bq, const float* __restrict__ bk, const float* __restrict__ bv,
    unsigned short* __restrict__ qo, unsigned short* __restrict__ ko,
    unsigned short* __restrict__ vto) {
  __shared__ unsigned short Ash[2][128 * 32];   // 2 x 8 KB
  __shared__ unsigned short Bsh[2][128 * 32];   // 2 x 8 KB
  const int tid = threadIdx.x, lane = tid & 63, wave = tid >> 6;
  const int l15 = lane & 15, quad = lane >> 4;
  const int wr = wave >> 1, wc = wave & 1;      // 2x2 waves, each 64x64 out
  const int bn = blockIdx.x * 128, bm = blockIdx.y * 128;
  const char* Ab = (const char*)(hb + (size_t)bm * HID);
  const char* Bb = (const char*)(wcat + (size_t)bn * HID);
  // staging: tile is [128 rows][32 cols] bf16 = 8 KB, linear; 2 issues x 256 lanes x 16B
  const int off = tid * 16;                 // issue-0 byte offset in tile
  const int r0 = off >> 6, c0 = off & 63;   // 64 B per row
  const size_t ga0 = (size_t)r0 * (HID * 2) + c0;
  const size_t ga1 = (size_t)(r0 + 64) * (HID * 2) + c0;
  const int lb0 = wave * 512;               // elements; HW adds lane*8
  const int lb1 = 2048 + wave * 512;

  f32x4 acc[4][4];
#pragma unroll
  for (int i = 0; i < 4; ++i)
#pragma unroll
    for (int j = 0; j < 4; ++j) acc[i][j] = f32x4{0.f, 0.f, 0.f, 0.f};

  // prologue: stage k0=0 into buf 0
  gll16(Ab + ga0, &Ash[0][lb0]);
  gll16(Ab + ga1, &Ash[0][lb1]);
  gll16(Bb + ga0, &Bsh[0][lb0]);
  gll16(Bb + ga1, &Bsh[0][lb1]);
  __syncthreads();

  for (int k0 = 0; k0 < HID; k0 += 32) {
    const int cur = (k0 >> 5) & 1;
    if (k0 + 32 < HID) {                     // prefetch next K-step into other buffer
      const size_t kb = (size_t)(k0 + 32) * 2;
      gll16(Ab + ga0 + kb, &Ash[cur ^ 1][lb0]);
      gll16(Ab + ga1 + kb, &Ash[cur ^ 1][lb1]);
      gll16(Bb + ga0 + kb, &Bsh[cur ^ 1][lb0]);
      gll16(Bb + ga1 + kb, &Bsh[cur ^ 1][lb1]);
    }
    s16x8 af[4], bfr[4];
#pragma unroll
    for (int i = 0; i < 4; ++i)
      af[i] = *(const s16x8*)(&Ash[cur][(wr * 64 + i * 16 + l15) * 32 + quad * 8]);
#pragma unroll
    for (int j = 0; j < 4; ++j)
      bfr[j] = *(const s16x8*)(&Bsh[cur][(wc * 64 + j * 16 + l15) * 32 + quad * 8]);
#pragma unroll
    for (int i = 0; i < 4; ++i)
#pragma unroll
      for (int j = 0; j < 4; ++j)
        acc[i][j] = __builtin_amdgcn_mfma_f32_16x16x32_bf16(af[i], bfr[j], acc[i][j], 0, 0, 0);
    __syncthreads();   // drains prefetch (overlapped with MFMA) + readers done with buf[cur]
  }

  const int mat = bn >> 10;                  // 0=Q 1=K 2=V (128-col blocks never straddle)
  const int cb = (bn & 1023) + wc * 64;
  const int rbase = bm + wr * 64;
  if (mat == 2) {
    // V: f16, transposed [B,NH,D,T]; 4 consecutive t per lane = 8B store
#pragma unroll
    for (int j = 0; j < 4; ++j) {
      const int coln = cb + j * 16 + l15;
      const int head = coln >> 6, d = coln & 63;
      const float bb = bv[coln];
#pragma unroll
      for (int i = 0; i < 4; ++i) {
        const int row0 = rbase + i * 16 + quad * 4;
        const int bI = row0 >> 11, t0 = row0 & 2047;
        unsigned short o[4];
#pragma unroll
        for (int r = 0; r < 4; ++r) {
          _Float16 hv = (_Float16)(acc[i][j][r] + bb);
          o[r] = __builtin_bit_cast(unsigned short, hv);
        }
        *(s16x4*)(vto + ((size_t)((bI * NH + head) * HD + d)) * TSEQ + t0) = *(const s16x4*)o;
      }
    }
  } else {
    unsigned short* dst = (mat == 0) ? qo : ko;
#pragma unroll
    for (int j = 0; j < 4; ++j) {
      const int coln = cb + j * 16 + l15;
      const int head = coln >> 6, d = coln & 63;
      const float bb = (mat == 0) ? bq[coln] : bk[coln] * KSCALE;
#pragma unroll
      for (int i = 0; i < 4; ++i) {
#pragma unroll
        for (int r = 0; r < 4; ++r) {
          const int row = rbase + i * 16 + quad * 4 + r;
          const int bI = row >> 11, t = row & 2047;
          dst[(((size_t)(bI * NH + head) * TSEQ) + t) * HD + d] = f2bf(acc[i][j][r] + bb);
        }
      }
    }
  }
}

// ---------------- Output projection: 128x64 tile, same gll+dbuf structure ----------------
__global__ __launch_bounds__(256) void gemm_out(
    const unsigned short* __restrict__ ctx, const unsigned short* __restrict__ wo,
    const float* __restrict__ bo, const float* __restrict__ hres,
    float* __restrict__ outf) {
  __shared__ unsigned short Ash[2][128 * 32];   // 2 x 8 KB
  __shared__ unsigned short Bsh[2][64 * 32];    // 2 x 4 KB
  const int tid = threadIdx.x, lane = tid & 63, wave = tid >> 6;
  const int l15 = lane & 15, quad = lane >> 4;
  const int wr = wave >> 1, wc = wave & 1;      // each wave: 64 rows x 32 cols
  const int bn = blockIdx.x * 64, bm = blockIdx.y * 128;
  const char* Ab = (const char*)(ctx + (size_t)bm * HID);
  const char* Bb = (const char*)(wo + (size_t)bn * HID);
  const int off = tid * 16;
  const int r0 = off >> 6, c0 = off & 63;
  const size_t ga0 = (size_t)r0 * (HID * 2) + c0;
  const size_t ga1 = (size_t)(r0 + 64) * (HID * 2) + c0;
  const int lb0 = wave * 512, lb1 = 2048 + wave * 512;

  f32x4 acc[4][2];
#pragma unroll
  for (int i = 0; i < 4; ++i)
#pragma unroll
    for (int j = 0; j < 2; ++j) acc[i][j] = f32x4{0.f, 0.f, 0.f, 0.f};

  gll16(Ab + ga0, &Ash[0][lb0]);
  gll16(Ab + ga1, &Ash[0][lb1]);
  gll16(Bb + ga0, &Bsh[0][lb0]);          // 64x32 tile = exactly one issue
  __syncthreads();

  for (int k0 = 0; k0 < HID; k0 += 32) {
    const int cur = (k0 >> 5) & 1;
    if (k0 + 32 < HID) {
      const size_t kb = (size_t)(k0 + 32) * 2;
      gll16(Ab + ga0 + kb, &Ash[cur ^ 1][lb0]);
      gll16(Ab + ga1 + kb, &Ash[cur ^ 1][lb1]);
      gll16(Bb + ga0 + kb, &Bsh[cur ^ 1][lb0]);
    }
    s16x8 af[4], bfr[2];
#pragma unroll
    for (int i = 0; i < 4; ++i)
      af[i] = *(const s16x8*)(&Ash[cur][(wr * 64 + i * 16 + l15) * 32 + quad * 8]);
#pragma unroll
    for (int j = 0; j < 2; ++j)
      bfr[j] = *(const s16x8*)(&Bsh[cur][(wc * 32 + j * 16 + l15) * 32 + quad * 8]);
#pragma unroll
    for (int i = 0; i < 4; ++i)
#pragma unroll
      for (int j = 0; j < 2; ++j)
        acc[i][j] = __builtin_amdgcn_mfma_f32_16x16x32_bf16(af[i], bfr[j], acc[i][j], 0, 0, 0);
    __syncthreads();
  }
#pragma unroll
  for (int j = 0; j < 2; ++j) {
    const int col = bn + wc * 32 + j * 16 + l15;
    const float bb = bo[col];
#pragma unroll
    for (int i = 0; i < 4; ++i) {
#pragma unroll
      for (int r = 0; r < 4; ++r) {
        const int row = bm + wr * 64 + i * 16 + quad * 4 + r;
        const size_t o = (size_t)row * HID + col;
        outf[o] = acc[i][j][r] + bb + hres[o];
      }
    }
  }
}

// ---------------- Flash attention: S^T formulation, K-split by 1/2 ----------------
__global__ __launch_bounds__(256, 2) void attn_k(
    const unsigned short* __restrict__ qb, const unsigned short* __restrict__ kb,
    const unsigned short* __restrict__ vt, unsigned short* __restrict__ ctx,
    unsigned short* __restrict__ Opart, float* __restrict__ rsumP,
    int lsplit, int ntiles) {
  __shared__ unsigned short Ksh[64 * 72];   // bf16 [key][d]
  __shared__ unsigned short Vsh[64 * 72];   // f16  [d][key]

  const int tid = threadIdx.x, lane = tid & 63, wave = tid >> 6;
  const int l15 = lane & 15, quad = lane >> 4;
  const int z = blockIdx.z;
  const int b = z >> lsplit;
  const int part = z & ((1 << lsplit) - 1);
  const int h = blockIdx.y, qt = blockIdx.x;
  const size_t ho = ((size_t)(b * NH + h)) * TSEQ * HD;
  const unsigned short* Qh = qb + ho;
  const unsigned short* Kh = kb + ho;
  const unsigned short* Vh = vt + ho;
  const int q0 = qt * 128 + wave * 32;
  const int kt0 = part * ntiles;

  s16x8 qf[2][2];
#pragma unroll
  for (int s = 0; s < 2; ++s)
#pragma unroll
    for (int ks = 0; ks < 2; ++ks)
      qf[s][ks] = *(const s16x8*)(Qh + (size_t)(q0 + s * 16 + l15) * HD + ks * 32 + quad * 8);

  f32x4 accO[4][2];   // O^T: [d-strip n2][q-col s], lane=(d=quad*4+r, q=l15)
  float rsum[2];
#pragma unroll
  for (int n2 = 0; n2 < 4; ++n2)
#pragma unroll
    for (int s = 0; s < 2; ++s) accO[n2][s] = f32x4{0.f, 0.f, 0.f, 0.f};
  rsum[0] = rsum[1] = 0.f;

  const int sr = tid >> 3, sc = (tid & 7) * 8;
  s16x8 kreg[2], vreg[2];
#pragma unroll
  for (int hf = 0; hf < 2; ++hf) {
    kreg[hf] = *(const s16x8*)(Kh + (size_t)(kt0 * 64 + sr + hf * 32) * HD + sc);
    vreg[hf] = *(const s16x8*)(Vh + (size_t)(sr + hf * 32) * TSEQ + kt0 * 64 + sc);
  }

  for (int kt = 0; kt < ntiles; ++kt) {
    __syncthreads();
#pragma unroll
    for (int hf = 0; hf < 2; ++hf) {
      *(s16x8*)(Ksh + (sr + hf * 32) * 72 + sc) = kreg[hf];
      *(s16x8*)(Vsh + (sr + hf * 32) * 72 + sc) = vreg[hf];
    }
    __syncthreads();
    if (kt + 1 < ntiles) {
      const int k0n = (kt0 + kt + 1) * 64;
#pragma unroll
      for (int hf = 0; hf < 2; ++hf) {
        kreg[hf] = *(const s16x8*)(Kh + (size_t)(k0n + sr + hf * 32) * HD + sc);
        vreg[hf] = *(const s16x8*)(Vh + (size_t)(sr + hf * 32) * TSEQ + k0n + sc);
      }
    }

    f32x4 accS[2][4];
#pragma unroll
    for (int s = 0; s < 2; ++s)
#pragma unroll
      for (int n = 0; n < 4; ++n) accS[s][n] = f32x4{0.f, 0.f, 0.f, 0.f};
#pragma unroll
    for (int ks = 0; ks < 2; ++ks) {
#pragma unroll
      for (int n = 0; n < 4; ++n) {
        s16x8 kf = *(const s16x8*)(Ksh + (n * 16 + l15) * 72 + ks * 32 + quad * 8);
#pragma unroll
        for (int s = 0; s < 2; ++s)
          accS[s][n] = __builtin_amdgcn_mfma_f32_16x16x32_bf16(kf, qf[s][ks], accS[s][n], 0, 0, 0);
      }
    }

    // raw v_exp_f32 (R10-verified: libm exp2f's fixup was the VALU bottleneck)
    f16x4 pB[2][4];
#pragma unroll
    for (int s = 0; s < 2; ++s)
#pragma unroll
      for (int n = 0; n < 4; ++n) {
        float e0 = __builtin_amdgcn_exp2f(accS[s][n][0]);
        float e1 = __builtin_amdgcn_exp2f(accS[s][n][1]);
        float e2 = __builtin_amdgcn_exp2f(accS[s][n][2]);
        float e3 = __builtin_amdgcn_exp2f(accS[s][n][3]);
        rsum[s] += (e0 + e1) + (e2 + e3);
        f16x2 lo = __builtin_bit_cast(f16x2, __builtin_amdgcn_cvt_pkrtz(e0, e1));
        f16x2 hi = __builtin_bit_cast(f16x2, __builtin_amdgcn_cvt_pkrtz(e2, e3));
        pB[s][n] = f16x4{lo[0], lo[1], hi[0], hi[1]};
      }

#pragma unroll
    for (int n = 0; n < 4; ++n) {
#pragma unroll
      for (int n2 = 0; n2 < 4; ++n2) {
        f16x4 vA = *(const f16x4*)(Vsh + (n2 * 16 + l15) * 72 + n * 16 + quad * 4);
#pragma unroll
        for (int s = 0; s < 2; ++s)
          accO[n2][s] = __builtin_amdgcn_mfma_f32_16x16x16f16(vA, pB[s][n], accO[n2][s], 0, 0, 0);
      }
    }
  }

#pragma unroll
  for (int s = 0; s < 2; ++s) {
    float t = rsum[s];
    t += __shfl_xor(t, 16, 64);
    t += __shfl_xor(t, 32, 64);
    rsum[s] = t;
  }

  if (lsplit) {
    const int slot = (part * BATCH + b) * NH + h;
    const size_t ob = (size_t)slot * TSEQ * HD;
#pragma unroll
    for (int s = 0; s < 2; ++s) {
      const int t = q0 + s * 16 + l15;
#pragma unroll
      for (int n2 = 0; n2 < 4; ++n2) {
        const int d0 = n2 * 16 + quad * 4;
        unsigned short o[4];
#pragma unroll
        for (int r = 0; r < 4; ++r) o[r] = f2bf(accO[n2][s][r]);
        *(s16x4*)(Opart + ob + (size_t)t * HD + d0) = *(const s16x4*)o;
      }
    }
    if (quad == 0) {
      const size_t rb = (size_t)slot * TSEQ;
#pragma unroll
      for (int s = 0; s < 2; ++s)
        rsumP[rb + q0 + s * 16 + l15] = rsum[s];
    }
  } else {
#pragma unroll
    for (int s = 0; s < 2; ++s) {
      const int t = q0 + s * 16 + l15;
      const float inv = 1.f / rsum[s];
#pragma unroll
      for (int n2 = 0; n2 < 4; ++n2) {
        const int d0 = n2 * 16 + quad * 4;
        unsigned short o[4];
#pragma unroll
        for (int r = 0; r < 4; ++r) o[r] = f2bf(accO[n2][s][r] * inv);
        *(s16x4*)(ctx + ((size_t)(b * TSEQ + t)) * HID + h * HD + d0) = *(const s16x4*)o;
      }
    }
  }
}

// ---------------- combine K-split parts: ctx = sum(O_p)/sum(r_p), bf16 ----------------
__global__ __launch_bounds__(256) void combine_k(
    const unsigned short* __restrict__ Opart, const float* __restrict__ rsumP,
    unsigned short* __restrict__ ctx, int nparts) {
  const int gtid = blockIdx.x * 256 + threadIdx.x;  // 524288 total
  const int d = (gtid & 7) * 8;
  const int rem = gtid >> 3;
  const int t = rem & 2047;
  const int bh = rem >> 11;          // b*NH + h  (0..31)
  float acc[8] = {0, 0, 0, 0, 0, 0, 0, 0};
  float rs = 0.f;
  for (int p = 0; p < nparts; ++p) {
    const int slot = p * 32 + bh;
    s16x8 a = *(const s16x8*)(Opart + ((size_t)slot * TSEQ + t) * HD + d);
#pragma unroll
    for (int j = 0; j < 8; ++j) acc[j] += bf2f(((const unsigned short*)&a)[j]);
    rs += rsumP[(size_t)slot * TSEQ + t];
  }
  const float inv = 1.f / rs;
  unsigned short o[8];
#pragma unroll
  for (int j = 0; j < 8; ++j) o[j] = f2bf(acc[j] * inv);
  const int b = bh >> 4, h = bh & 15;
  *(s16x8*)(ctx + ((size_t)(b * TSEQ + t)) * HID + h * HD + d) = *(const s16x8*)o;
}

// ---------------- In-place LayerNorm over rows of 1024 ----------------
__global__ __launch_bounds__(256) void ln_k(float* __restrict__ io,
                                            const float* __restrict__ gamma,
                                            const float* __restrict__ beta) {
  const int row = blockIdx.x, tid = threadIdx.x;
  float x[4]; float s = 0.f, s2 = 0.f;
#pragma unroll
  for (int i = 0; i < 4; ++i) {
    x[i] = io[(size_t)row * HID + tid + i * 256];
    s += x[i]; s2 += x[i] * x[i];
  }
#pragma unroll
  for (int off = 1; off < 64; off <<= 1) {
    s  += __shfl_xor(s, off, 64);
    s2 += __shfl_xor(s2, off, 64);
  }
  __shared__ float red[8];
  const int wave = tid >> 6;
  if ((tid & 63) == 0) { red[wave] = s; red[wave + 4] = s2; }
  __syncthreads();
  s  = red[0] + red[1] + red[2] + red[3];
  s2 = red[4] + red[5] + red[6] + red[7];
  const float mean = s * (1.f / HID);
  const float var  = s2 * (1.f / HID) - mean * mean;
  const float rstd = rsqrtf(var + 1e-6f);
#pragma unroll
  for (int i = 0; i < 4; ++i) {
    const int col = tid + i * 256;
    io[(size_t)row * HID + col] = (x[i] - mean) * rstd * gamma[col] + beta[col];
  }
}

extern "C" void kernel_launch(void* const* d_in, const int* in_sizes, int n_in,
                              void* d_out, int out_size, void* d_ws, size_t ws_size,
                              hipStream_t stream) {
  const float* h    = (const float*)d_in[0];
  const float* Wq   = (const float*)d_in[1];
  const float* bq   = (const float*)d_in[2];
  const float* Wk   = (const float*)d_in[3];
  const float* bk   = (const float*)d_in[4];
  const float* Wv   = (const float*)d_in[5];
  const float* bv   = (const float*)d_in[6];
  const float* Wo   = (const float*)d_in[7];
  const float* bo   = (const float*)d_in[8];
  const float* gamma = (const float*)d_in[9];
  const float* beta  = (const float*)d_in[10];
  float* out = (float*)d_out;

  unsigned short* hb   = (unsigned short*)d_ws;   // bf16 h; dead after gemm_qkv -> reused as ctx
  unsigned short* wqb  = hb  + 4194304;           // 4 weights contiguous (Wq|Wk|Wv|Wo)
  unsigned short* wkb  = wqb + 1048576;
  unsigned short* wvb  = wkb + 1048576;
  unsigned short* wob  = wvb + 1048576;
  unsigned short* qb   = wob + 1048576;           // bf16 [B,NH,T,D]
  unsigned short* kb   = qb  + 4194304;
  unsigned short* vtf  = kb  + 4194304;           // f16 [B,NH,D,T], written by gemm_qkv directly
  unsigned short* Opart = vtf + 4194304;          // bf16 partials (2 parts x 8 MiB)
  unsigned short* ctxb = hb;                      // ctx aliases dead hb

  const size_t base = (size_t)(vtf + 4194304 - hb) * 2;  // bytes before Opart (40 MiB)
  int lsplit = 0;
  if (ws_size >= base + 2u * 8388608 + 2u * 262144) lsplit = 1;  // ~57 MiB
  const int nparts = 1 << lsplit;
  float* rsumP = (float*)(Opart + (size_t)nparts * 4194304);

  cast_all_k<<<8192, 256, 0, stream>>>(h, Wq, Wk, Wv, Wo, hb, wqb);
  gemm_qkv<<<dim3(24, 32), 256, 0, stream>>>(hb, wqb, bq, bk, bv, qb, kb, vtf);
  attn_k<<<dim3(TSEQ / 128, NH, BATCH << lsplit), 256, 0, stream>>>(
      qb, kb, vtf, ctxb, Opart, rsumP, lsplit, 32 >> lsplit);
  if (lsplit)
    combine_k<<<2048, 256, 0, stream>>>(Opart, rsumP, ctxb, nparts);
  gemm_out<<<dim3(16, 32), 256, 0, stream>>>(ctxb, wob, bo, h, out);
  ln_k<<<4096, 256, 0, stream>>>(out, gamma, beta);
}

// Round 2
// 234.858 us; speedup vs baseline: 1.0046x; 1.0046x over previous
//
#include <hip/hip_runtime.h>
#include <hip/hip_bf16.h>

#define NH   16
#define HD   64
#define HID  1024
#define TSEQ 2048
#define BATCH 2
#define KSCALE 0.18033688011112042f   // 0.125 * log2(e), folded into Wk/bk

typedef __attribute__((ext_vector_type(4))) float f32x4;
typedef __attribute__((ext_vector_type(8))) short s16x8;
typedef __attribute__((ext_vector_type(4))) short s16x4;
typedef __attribute__((ext_vector_type(8))) _Float16 f16x8;
typedef __attribute__((ext_vector_type(4))) _Float16 f16x4;
typedef __attribute__((ext_vector_type(2))) _Float16 f16x2;

__device__ __forceinline__ unsigned short f2bf(float f) {
  union { float f; unsigned int u; } v; v.f = f;
  unsigned int r = v.u + 0x7fffu + ((v.u >> 16) & 1u);
  return (unsigned short)(r >> 16);
}
__device__ __forceinline__ float bf2f(unsigned short b) {
  union { unsigned int u; float f; } v; v.u = ((unsigned int)b) << 16; return v.f;
}

// async global->LDS, 16B per lane; LDS dest must be wave-uniform base (+lane*16 by HW)
__device__ __forceinline__ void gll16(const void* g, void* l) {
  __builtin_amdgcn_global_load_lds(
      (const __attribute__((address_space(1))) unsigned int*)g,
      (__attribute__((address_space(3))) unsigned int*)l, 16, 0, 0);
}

// counted-vmcnt barrier: own-wave loads <= N outstanding, then collective barrier.
// sched_barrier(0) pins all prior instrs (incl. MFMAs + their lgkm waits) before it.
#define WAITBAR(N)                                                      \
  do {                                                                  \
    __builtin_amdgcn_sched_barrier(0);                                  \
    asm volatile("s_waitcnt vmcnt(" #N ")\n\ts_barrier" ::: "memory");  \
  } while (0)

// ---------------- one cast kernel: h + all 4 weights (Wk pre-scaled) ----------------
__global__ __launch_bounds__(256) void cast_all_k(
    const float* __restrict__ h,
    const float* __restrict__ w0, const float* __restrict__ w1,
    const float* __restrict__ w2, const float* __restrict__ w3,
    unsigned short* __restrict__ hb, unsigned short* __restrict__ wbase) {
  int i = blockIdx.x * 256 + threadIdx.x;  // 2097152 float4 total
  const float* src; unsigned short* dst; int idx; float sc = 1.f;
  if (i < 1048576) { src = h; dst = hb; idx = i; }
  else {
    int idx4 = i - 1048576;
    int w = idx4 >> 18;
    idx = idx4 & 262143;
    src = (w == 0) ? w0 : (w == 1) ? w1 : (w == 2) ? w2 : w3;
    dst = wbase + (size_t)(idx4 - idx) * 4;   // contiguous weight region
    if (w == 1) sc = KSCALE;
  }
  float4 v = ((const float4*)src)[idx];
  ushort4 o;
  o.x = f2bf(v.x * sc); o.y = f2bf(v.y * sc); o.z = f2bf(v.z * sc); o.w = f2bf(v.w * sc);
  ((ushort4*)dst)[idx] = o;
}

// ---------------- Fused QKV projection: one 4096x3072x1024 NT-GEMM ----------------
// 3-buffer LDS ring, global_load_lds staging, counted vmcnt (never 0 in loop),
// XOR-swizzled LDS (linear dest + pre-swizzled global source + swizzled read).
__global__ __launch_bounds__(256) void gemm_qkv(
    const unsigned short* __restrict__ hb,
    const unsigned short* __restrict__ wcat,   // [3072][1024] = Wq|Wk|Wv, Wk pre-scaled
    const float* __restrict__ bq, const float* __restrict__ bk, const float* __restrict__ bv,
    unsigned short* __restrict__ qo, unsigned short* __restrict__ ko,
    unsigned short* __restrict__ vto) {
  __shared__ unsigned short Ash[3][128 * 32];   // 3 x 8 KB
  __shared__ unsigned short Bsh[3][128 * 32];   // 3 x 8 KB
  const int tid = threadIdx.x, lane = tid & 63, wave = tid >> 6;
  const int l15 = lane & 15, quad = lane >> 4;
  const int wr = wave >> 1, wc = wave & 1;      // 2x2 waves, each 64x64 out
  const int bn = blockIdx.x * 128, bm = blockIdx.y * 128;
  const char* Ab = (const char*)(hb + (size_t)bm * HID);
  const char* Bb = (const char*)(wcat + (size_t)bn * HID);
  // Staging: tile [128 r][32 k] bf16 = 8 KB linear in LDS; 2 issues x 256 lanes x 16B.
  // Global source pre-swizzled: LDS chunk (r,q) holds tile data (r, q^(r&3)).
  const int off = tid * 16;                 // LDS byte offset this thread covers (issue 0)
  const int r0 = off >> 6;                  // tile row (64 B per row)
  const int q0i = (off >> 4) & 3;           // 16B chunk within row
  const int c0 = (q0i ^ (r0 & 3)) << 4;     // swizzled source col (bytes); r&3 same for r0+64
  const size_t ga0 = (size_t)r0 * (HID * 2) + c0;
  const size_t ga1 = ga0 + (size_t)64 * (HID * 2);
  const int lb0 = wave * 512;               // LDS dest (elements); HW adds lane*16B
  const int lb1 = 2048 + wave * 512;

  f32x4 acc[4][4];
#pragma unroll
  for (int i = 0; i < 4; ++i)
#pragma unroll
    for (int j = 0; j < 4; ++j) acc[i][j] = f32x4{0.f, 0.f, 0.f, 0.f};

  auto stage = [&](int bufi, int k0) {
    const size_t kb = (size_t)k0 * 2;
    gll16(Ab + ga0 + kb, &Ash[bufi][lb0]);
    gll16(Ab + ga1 + kb, &Ash[bufi][lb1]);
    gll16(Bb + ga0 + kb, &Bsh[bufi][lb0]);
    gll16(Bb + ga1 + kb, &Bsh[bufi][lb1]);
  };
  const int qx = (quad ^ (l15 & 3)) * 8;    // swizzled k-chunk for reads (row&3 == l15&3)
  auto compute = [&](int bufi) {
    s16x8 af[4], bfr[4];
#pragma unroll
    for (int i = 0; i < 4; ++i)
      af[i] = *(const s16x8*)(&Ash[bufi][(wr * 64 + i * 16 + l15) * 32 + qx]);
#pragma unroll
    for (int j = 0; j < 4; ++j)
      bfr[j] = *(const s16x8*)(&Bsh[bufi][(wc * 64 + j * 16 + l15) * 32 + qx]);
#pragma unroll
    for (int i = 0; i < 4; ++i)
#pragma unroll
      for (int j = 0; j < 4; ++j)
        acc[i][j] = __builtin_amdgcn_mfma_f32_16x16x32_bf16(af[i], bfr[j], acc[i][j], 0, 0, 0);
  };

  // prologue: tiles 0,1 in flight (8 outstanding/wave)
  stage(0, 0);
  stage(1, 32);
  int cur = 0, pf = 2;
  const int NT = HID / 32;                  // 32
  for (int t = 0; t < NT - 1; ++t) {
    WAITBAR(4);                             // tile t landed (tile t+1 stays in flight)
    if (t + 2 < NT) stage(pf, (t + 2) * 32);
    compute(cur);
    cur = (cur == 2) ? 0 : cur + 1;
    pf  = (pf  == 2) ? 0 : pf + 1;
  }
  WAITBAR(0);                               // drain last tile
  compute(cur);

  const int mat = bn >> 10;                  // 0=Q 1=K 2=V (128-col blocks never straddle)
  const int cb = (bn & 1023) + wc * 64;
  const int rbase = bm + wr * 64;
  if (mat == 2) {
    // V: f16, transposed [B,NH,D,T]; 4 consecutive t per lane = 8B store
#pragma unroll
    for (int j = 0; j < 4; ++j) {
      const int coln = cb + j * 16 + l15;
      const int head = coln >> 6, d = coln & 63;
      const float bb = bv[coln];
#pragma unroll
      for (int i = 0; i < 4; ++i) {
        const int row0 = rbase + i * 16 + quad * 4;
        const int bI = row0 >> 11, t0 = row0 & 2047;
        unsigned short o[4];
#pragma unroll
        for (int r = 0; r < 4; ++r) {
          _Float16 hv = (_Float16)(acc[i][j][r] + bb);
          o[r] = __builtin_bit_cast(unsigned short, hv);
        }
        *(s16x4*)(vto + ((size_t)((bI * NH + head) * HD + d)) * TSEQ + t0) = *(const s16x4*)o;
      }
    }
  } else {
    unsigned short* dst = (mat == 0) ? qo : ko;
#pragma unroll
    for (int j = 0; j < 4; ++j) {
      const int coln = cb + j * 16 + l15;
      const int head = coln >> 6, d = coln & 63;
      const float bb = (mat == 0) ? bq[coln] : bk[coln] * KSCALE;
#pragma unroll
      for (int i = 0; i < 4; ++i) {
#pragma unroll
        for (int r = 0; r < 4; ++r) {
          const int row = rbase + i * 16 + quad * 4 + r;
          const int bI = row >> 11, t = row & 2047;
          dst[(((size_t)(bI * NH + head) * TSEQ) + t) * HD + d] = f2bf(acc[i][j][r] + bb);
        }
      }
    }
  }
}

// ---------------- Output projection: 128x64 tile, same ring structure ----------------
__global__ __launch_bounds__(256) void gemm_out(
    const unsigned short* __restrict__ ctx, const unsigned short* __restrict__ wo,
    const float* __restrict__ bo, const float* __restrict__ hres,
    float* __restrict__ outf) {
  __shared__ unsigned short Ash[3][128 * 32];   // 3 x 8 KB
  __shared__ unsigned short Bsh[3][64 * 32];    // 3 x 4 KB
  const int tid = threadIdx.x, lane = tid & 63, wave = tid >> 6;
  const int l15 = lane & 15, quad = lane >> 4;
  const int wr = wave >> 1, wc = wave & 1;      // each wave: 64 rows x 32 cols
  const int bn = blockIdx.x * 64, bm = blockIdx.y * 128;
  const char* Ab = (const char*)(ctx + (size_t)bm * HID);
  const char* Bb = (const char*)(wo + (size_t)bn * HID);
  const int off = tid * 16;
  const int r0 = off >> 6;
  const int q0i = (off >> 4) & 3;
  const int c0 = (q0i ^ (r0 & 3)) << 4;
  const size_t ga0 = (size_t)r0 * (HID * 2) + c0;
  const size_t ga1 = ga0 + (size_t)64 * (HID * 2);
  const int lb0 = wave * 512, lb1 = 2048 + wave * 512;

  f32x4 acc[4][2];
#pragma unroll
  for (int i = 0; i < 4; ++i)
#pragma unroll
    for (int j = 0; j < 2; ++j) acc[i][j] = f32x4{0.f, 0.f, 0.f, 0.f};

  auto stage = [&](int bufi, int k0) {
    const size_t kb = (size_t)k0 * 2;
    gll16(Ab + ga0 + kb, &Ash[bufi][lb0]);
    gll16(Ab + ga1 + kb, &Ash[bufi][lb1]);
    gll16(Bb + ga0 + kb, &Bsh[bufi][lb0]);   // 64x32 B-tile = exactly one issue
  };
  const int qx = (quad ^ (l15 & 3)) * 8;
  auto compute = [&](int bufi) {
    s16x8 af[4], bfr[2];
#pragma unroll
    for (int i = 0; i < 4; ++i)
      af[i] = *(const s16x8*)(&Ash[bufi][(wr * 64 + i * 16 + l15) * 32 + qx]);
#pragma unroll
    for (int j = 0; j < 2; ++j)
      bfr[j] = *(const s16x8*)(&Bsh[bufi][(wc * 32 + j * 16 + l15) * 32 + qx]);
#pragma unroll
    for (int i = 0; i < 4; ++i)
#pragma unroll
      for (int j = 0; j < 2; ++j)
        acc[i][j] = __builtin_amdgcn_mfma_f32_16x16x32_bf16(af[i], bfr[j], acc[i][j], 0, 0, 0);
  };

  stage(0, 0);
  stage(1, 32);
  int cur = 0, pf = 2;
  const int NT = HID / 32;
  for (int t = 0; t < NT - 1; ++t) {
    WAITBAR(3);                             // 3 loads/tile: tile t done, t+1 in flight
    if (t + 2 < NT) stage(pf, (t + 2) * 32);
    compute(cur);
    cur = (cur == 2) ? 0 : cur + 1;
    pf  = (pf  == 2) ? 0 : pf + 1;
  }
  WAITBAR(0);
  compute(cur);

#pragma unroll
  for (int j = 0; j < 2; ++j) {
    const int col = bn + wc * 32 + j * 16 + l15;
    const float bb = bo[col];
#pragma unroll
    for (int i = 0; i < 4; ++i) {
#pragma unroll
      for (int r = 0; r < 4; ++r) {
        const int row = bm + wr * 64 + i * 16 + quad * 4 + r;
        const size_t o = (size_t)row * HID + col;
        outf[o] = acc[i][j][r] + bb + hres[o];
      }
    }
  }
}

// ---------------- Flash attention: S^T formulation, K-split by 1/2 ----------------
__global__ __launch_bounds__(256, 2) void attn_k(
    const unsigned short* __restrict__ qb, const unsigned short* __restrict__ kb,
    const unsigned short* __restrict__ vt, unsigned short* __restrict__ ctx,
    unsigned short* __restrict__ Opart, float* __restrict__ rsumP,
    int lsplit, int ntiles) {
  __shared__ unsigned short Ksh[64 * 72];   // bf16 [key][d]
  __shared__ unsigned short Vsh[64 * 72];   // f16  [d][key]

  const int tid = threadIdx.x, lane = tid & 63, wave = tid >> 6;
  const int l15 = lane & 15, quad = lane >> 4;
  const int z = blockIdx.z;
  const int b = z >> lsplit;
  const int part = z & ((1 << lsplit) - 1);
  const int h = blockIdx.y, qt = blockIdx.x;
  const size_t ho = ((size_t)(b * NH + h)) * TSEQ * HD;
  const unsigned short* Qh = qb + ho;
  const unsigned short* Kh = kb + ho;
  const unsigned short* Vh = vt + ho;
  const int q0 = qt * 128 + wave * 32;
  const int kt0 = part * ntiles;

  s16x8 qf[2][2];
#pragma unroll
  for (int s = 0; s < 2; ++s)
#pragma unroll
    for (int ks = 0; ks < 2; ++ks)
      qf[s][ks] = *(const s16x8*)(Qh + (size_t)(q0 + s * 16 + l15) * HD + ks * 32 + quad * 8);

  f32x4 accO[4][2];   // O^T: [d-strip n2][q-col s], lane=(d=quad*4+r, q=l15)
  float rsum[2];
#pragma unroll
  for (int n2 = 0; n2 < 4; ++n2)
#pragma unroll
    for (int s = 0; s < 2; ++s) accO[n2][s] = f32x4{0.f, 0.f, 0.f, 0.f};
  rsum[0] = rsum[1] = 0.f;

  const int sr = tid >> 3, sc = (tid & 7) * 8;
  s16x8 kreg[2], vreg[2];
#pragma unroll
  for (int hf = 0; hf < 2; ++hf) {
    kreg[hf] = *(const s16x8*)(Kh + (size_t)(kt0 * 64 + sr + hf * 32) * HD + sc);
    vreg[hf] = *(const s16x8*)(Vh + (size_t)(sr + hf * 32) * TSEQ + kt0 * 64 + sc);
  }

  for (int kt = 0; kt < ntiles; ++kt) {
    __syncthreads();
#pragma unroll
    for (int hf = 0; hf < 2; ++hf) {
      *(s16x8*)(Ksh + (sr + hf * 32) * 72 + sc) = kreg[hf];
      *(s16x8*)(Vsh + (sr + hf * 32) * 72 + sc) = vreg[hf];
    }
    __syncthreads();
    if (kt + 1 < ntiles) {
      const int k0n = (kt0 + kt + 1) * 64;
#pragma unroll
      for (int hf = 0; hf < 2; ++hf) {
        kreg[hf] = *(const s16x8*)(Kh + (size_t)(k0n + sr + hf * 32) * HD + sc);
        vreg[hf] = *(const s16x8*)(Vh + (size_t)(sr + hf * 32) * TSEQ + k0n + sc);
      }
    }

    f32x4 accS[2][4];
#pragma unroll
    for (int s = 0; s < 2; ++s)
#pragma unroll
      for (int n = 0; n < 4; ++n) accS[s][n] = f32x4{0.f, 0.f, 0.f, 0.f};
#pragma unroll
    for (int ks = 0; ks < 2; ++ks) {
#pragma unroll
      for (int n = 0; n < 4; ++n) {
        s16x8 kf = *(const s16x8*)(Ksh + (n * 16 + l15) * 72 + ks * 32 + quad * 8);
#pragma unroll
        for (int s = 0; s < 2; ++s)
          accS[s][n] = __builtin_amdgcn_mfma_f32_16x16x32_bf16(kf, qf[s][ks], accS[s][n], 0, 0, 0);
      }
    }

    // raw v_exp_f32 (R10-verified: libm exp2f's fixup was the VALU bottleneck)
    f16x4 pB[2][4];
#pragma unroll
    for (int s = 0; s < 2; ++s)
#pragma unroll
      for (int n = 0; n < 4; ++n) {
        float e0 = __builtin_amdgcn_exp2f(accS[s][n][0]);
        float e1 = __builtin_amdgcn_exp2f(accS[s][n][1]);
        float e2 = __builtin_amdgcn_exp2f(accS[s][n][2]);
        float e3 = __builtin_amdgcn_exp2f(accS[s][n][3]);
        rsum[s] += (e0 + e1) + (e2 + e3);
        f16x2 lo = __builtin_bit_cast(f16x2, __builtin_amdgcn_cvt_pkrtz(e0, e1));
        f16x2 hi = __builtin_bit_cast(f16x2, __builtin_amdgcn_cvt_pkrtz(e2, e3));
        pB[s][n] = f16x4{lo[0], lo[1], hi[0], hi[1]};
      }

#pragma unroll
    for (int n = 0; n < 4; ++n) {
#pragma unroll
      for (int n2 = 0; n2 < 4; ++n2) {
        f16x4 vA = *(const f16x4*)(Vsh + (n2 * 16 + l15) * 72 + n * 16 + quad * 4);
#pragma unroll
        for (int s = 0; s < 2; ++s)
          accO[n2][s] = __builtin_amdgcn_mfma_f32_16x16x16f16(vA, pB[s][n], accO[n2][s], 0, 0, 0);
      }
    }
  }

#pragma unroll
  for (int s = 0; s < 2; ++s) {
    float t = rsum[s];
    t += __shfl_xor(t, 16, 64);
    t += __shfl_xor(t, 32, 64);
    rsum[s] = t;
  }

  if (lsplit) {
    const int slot = (part * BATCH + b) * NH + h;
    const size_t ob = (size_t)slot * TSEQ * HD;
#pragma unroll
    for (int s = 0; s < 2; ++s) {
      const int t = q0 + s * 16 + l15;
#pragma unroll
      for (int n2 = 0; n2 < 4; ++n2) {
        const int d0 = n2 * 16 + quad * 4;
        unsigned short o[4];
#pragma unroll
        for (int r = 0; r < 4; ++r) o[r] = f2bf(accO[n2][s][r]);
        *(s16x4*)(Opart + ob + (size_t)t * HD + d0) = *(const s16x4*)o;
      }
    }
    if (quad == 0) {
      const size_t rb = (size_t)slot * TSEQ;
#pragma unroll
      for (int s = 0; s < 2; ++s)
        rsumP[rb + q0 + s * 16 + l15] = rsum[s];
    }
  } else {
#pragma unroll
    for (int s = 0; s < 2; ++s) {
      const int t = q0 + s * 16 + l15;
      const float inv = 1.f / rsum[s];
#pragma unroll
      for (int n2 = 0; n2 < 4; ++n2) {
        const int d0 = n2 * 16 + quad * 4;
        unsigned short o[4];
#pragma unroll
        for (int r = 0; r < 4; ++r) o[r] = f2bf(accO[n2][s][r] * inv);
        *(s16x4*)(ctx + ((size_t)(b * TSEQ + t)) * HID + h * HD + d0) = *(const s16x4*)o;
      }
    }
  }
}

// ---------------- combine K-split parts: ctx = sum(O_p)/sum(r_p), bf16 ----------------
__global__ __launch_bounds__(256) void combine_k(
    const unsigned short* __restrict__ Opart, const float* __restrict__ rsumP,
    unsigned short* __restrict__ ctx, int nparts) {
  const int gtid = blockIdx.x * 256 + threadIdx.x;  // 524288 total
  const int d = (gtid & 7) * 8;
  const int rem = gtid >> 3;
  const int t = rem & 2047;
  const int bh = rem >> 11;          // b*NH + h  (0..31)
  float acc[8] = {0, 0, 0, 0, 0, 0, 0, 0};
  float rs = 0.f;
  for (int p = 0; p < nparts; ++p) {
    const int slot = p * 32 + bh;
    s16x8 a = *(const s16x8*)(Opart + ((size_t)slot * TSEQ + t) * HD + d);
#pragma unroll
    for (int j = 0; j < 8; ++j) acc[j] += bf2f(((const unsigned short*)&a)[j]);
    rs += rsumP[(size_t)slot * TSEQ + t];
  }
  const float inv = 1.f / rs;
  unsigned short o[8];
#pragma unroll
  for (int j = 0; j < 8; ++j) o[j] = f2bf(acc[j] * inv);
  const int b = bh >> 4, h = bh & 15;
  *(s16x8*)(ctx + ((size_t)(b * TSEQ + t)) * HID + h * HD + d) = *(const s16x8*)o;
}

// ---------------- In-place LayerNorm over rows of 1024 ----------------
__global__ __launch_bounds__(256) void ln_k(float* __restrict__ io,
                                            const float* __restrict__ gamma,
                                            const float* __restrict__ beta) {
  const int row = blockIdx.x, tid = threadIdx.x;
  float x[4]; float s = 0.f, s2 = 0.f;
#pragma unroll
  for (int i = 0; i < 4; ++i) {
    x[i] = io[(size_t)row * HID + tid + i * 256];
    s += x[i]; s2 += x[i] * x[i];
  }
#pragma unroll
  for (int off = 1; off < 64; off <<= 1) {
    s  += __shfl_xor(s, off, 64);
    s2 += __shfl_xor(s2, off, 64);
  }
  __shared__ float red[8];
  const int wave = tid >> 6;
  if ((tid & 63) == 0) { red[wave] = s; red[wave + 4] = s2; }
  __syncthreads();
  s  = red[0] + red[1] + red[2] + red[3];
  s2 = red[4] + red[5] + red[6] + red[7];
  const float mean = s * (1.f / HID);
  const float var  = s2 * (1.f / HID) - mean * mean;
  const float rstd = rsqrtf(var + 1e-6f);
#pragma unroll
  for (int i = 0; i < 4; ++i) {
    const int col = tid + i * 256;
    io[(size_t)row * HID + col] = (x[i] - mean) * rstd * gamma[col] + beta[col];
  }
}

extern "C" void kernel_launch(void* const* d_in, const int* in_sizes, int n_in,
                              void* d_out, int out_size, void* d_ws, size_t ws_size,
                              hipStream_t stream) {
  const float* h    = (const float*)d_in[0];
  const float* Wq   = (const float*)d_in[1];
  const float* bq   = (const float*)d_in[2];
  const float* Wk   = (const float*)d_in[3];
  const float* bk   = (const float*)d_in[4];
  const float* Wv   = (const float*)d_in[5];
  const float* bv   = (const float*)d_in[6];
  const float* Wo   = (const float*)d_in[7];
  const float* bo   = (const float*)d_in[8];
  const float* gamma = (const float*)d_in[9];
  const float* beta  = (const float*)d_in[10];
  float* out = (float*)d_out;

  unsigned short* hb   = (unsigned short*)d_ws;   // bf16 h; dead after gemm_qkv -> reused as ctx
  unsigned short* wqb  = hb  + 4194304;           // 4 weights contiguous (Wq|Wk|Wv|Wo)
  unsigned short* wkb  = wqb + 1048576;
  unsigned short* wvb  = wkb + 1048576;
  unsigned short* wob  = wvb + 1048576;
  unsigned short* qb   = wob + 1048576;           // bf16 [B,NH,T,D]
  unsigned short* kb   = qb  + 4194304;
  unsigned short* vtf  = kb  + 4194304;           // f16 [B,NH,D,T], written by gemm_qkv directly
  unsigned short* Opart = vtf + 4194304;          // bf16 partials (2 parts x 8 MiB)
  unsigned short* ctxb = hb;                      // ctx aliases dead hb

  const size_t base = (size_t)(vtf + 4194304 - hb) * 2;  // bytes before Opart (40 MiB)
  int lsplit = 0;
  if (ws_size >= base + 2u * 8388608 + 2u * 262144) lsplit = 1;  // ~57 MiB
  const int nparts = 1 << lsplit;
  float* rsumP = (float*)(Opart + (size_t)nparts * 4194304);

  cast_all_k<<<8192, 256, 0, stream>>>(h, Wq, Wk, Wv, Wo, hb, wqb);
  gemm_qkv<<<dim3(24, 32), 256, 0, stream>>>(hb, wqb, bq, bk, bv, qb, kb, vtf);
  attn_k<<<dim3(TSEQ / 128, NH, BATCH << lsplit), 256, 0, stream>>>(
      qb, kb, vtf, ctxb, Opart, rsumP, lsplit, 32 >> lsplit);
  if (lsplit)
    combine_k<<<2048, 256, 0, stream>>>(Opart, rsumP, ctxb, nparts);
  gemm_out<<<dim3(16, 32), 256, 0, stream>>>(ctxb, wob, bo, h, out);
  ln_k<<<4096, 256, 0, stream>>>(out, gamma, beta);
}

// Round 3
// 221.278 us; speedup vs baseline: 1.0662x; 1.0614x over previous
//
#include <hip/hip_runtime.h>
#include <hip/hip_bf16.h>

#define NH   16
#define HD   64
#define HID  1024
#define TSEQ 2048
#define BATCH 2
#define KSCALE 0.18033688011112042f   // 0.125 * log2(e), folded into Wk/bk

typedef __attribute__((ext_vector_type(4))) float f32x4;
typedef __attribute__((ext_vector_type(8))) short s16x8;
typedef __attribute__((ext_vector_type(4))) short s16x4;
typedef __attribute__((ext_vector_type(8))) _Float16 f16x8;
typedef __attribute__((ext_vector_type(4))) _Float16 f16x4;
typedef __attribute__((ext_vector_type(2))) _Float16 f16x2;

__device__ __forceinline__ unsigned short f2bf(float f) {
  union { float f; unsigned int u; } v; v.f = f;
  unsigned int r = v.u + 0x7fffu + ((v.u >> 16) & 1u);
  return (unsigned short)(r >> 16);
}
__device__ __forceinline__ float bf2f(unsigned short b) {
  union { unsigned int u; float f; } v; v.u = ((unsigned int)b) << 16; return v.f;
}

// async global->LDS, 16B per lane; LDS dest must be wave-uniform base (+lane*16 by HW)
__device__ __forceinline__ void gll16(const void* g, void* l) {
  __builtin_amdgcn_global_load_lds(
      (const __attribute__((address_space(1))) unsigned int*)g,
      (__attribute__((address_space(3))) unsigned int*)l, 16, 0, 0);
}

// counted-vmcnt barrier: own-wave outstanding loads <= N, then collective barrier.
// vmcnt BEFORE s_barrier makes the per-wave count a collective guarantee.
// sched_barrier(0) pins prior MFMAs (and their lgkm waits) before it (rule 18).
#define WAITBAR(N)                                                      \
  do {                                                                  \
    __builtin_amdgcn_sched_barrier(0);                                  \
    asm volatile("s_waitcnt vmcnt(" #N ")\n\ts_barrier" ::: "memory");  \
  } while (0)

// ---------------- one cast kernel: h + all 4 weights (Wk pre-scaled) ----------------
__global__ __launch_bounds__(256) void cast_all_k(
    const float* __restrict__ h,
    const float* __restrict__ w0, const float* __restrict__ w1,
    const float* __restrict__ w2, const float* __restrict__ w3,
    unsigned short* __restrict__ hb, unsigned short* __restrict__ wbase) {
  int i = blockIdx.x * 256 + threadIdx.x;  // 2097152 float4 total
  const float* src; unsigned short* dst; int idx; float sc = 1.f;
  if (i < 1048576) { src = h; dst = hb; idx = i; }
  else {
    int idx4 = i - 1048576;
    int w = idx4 >> 18;
    idx = idx4 & 262143;
    src = (w == 0) ? w0 : (w == 1) ? w1 : (w == 2) ? w2 : w3;
    dst = wbase + (size_t)(idx4 - idx) * 4;   // contiguous weight region
    if (w == 1) sc = KSCALE;
  }
  float4 v = ((const float4*)src)[idx];
  ushort4 o;
  o.x = f2bf(v.x * sc); o.y = f2bf(v.y * sc); o.z = f2bf(v.z * sc); o.w = f2bf(v.w * sc);
  ((ushort4*)dst)[idx] = o;
}

// ---------------- Fused QKV projection: one 4096x3072x1024 NT-GEMM ----------------
// 5-buffer LDS ring, prefetch distance 4 (covers ~4 phases of load latency),
// global_load_lds staging, counted vmcnt ladder (never 0 in main loop).
__global__ __launch_bounds__(256) void gemm_qkv(
    const unsigned short* __restrict__ hb,
    const unsigned short* __restrict__ wcat,   // [3072][1024] = Wq|Wk|Wv, Wk pre-scaled
    const float* __restrict__ bq, const float* __restrict__ bk, const float* __restrict__ bv,
    unsigned short* __restrict__ qo, unsigned short* __restrict__ ko,
    unsigned short* __restrict__ vto) {
  __shared__ unsigned short Ash[5][128 * 32];   // 5 x 8 KB
  __shared__ unsigned short Bsh[5][128 * 32];   // 5 x 8 KB  (total 80 KB -> 2 blocks/CU)
  const int tid = threadIdx.x, lane = tid & 63, wave = tid >> 6;
  const int l15 = lane & 15, quad = lane >> 4;
  const int wr = wave >> 1, wc = wave & 1;      // 2x2 waves, each 64x64 out
  const int bn = blockIdx.x * 128, bm = blockIdx.y * 128;
  const char* Ab = (const char*)(hb + (size_t)bm * HID);
  const char* Bb = (const char*)(wcat + (size_t)bn * HID);
  // staging: tile [128 r][32 k] bf16 = 8 KB linear; 2 issues x 256 lanes x 16B
  const int off = tid * 16;                 // LDS byte offset this thread covers (issue 0)
  const int r0 = off >> 6, c0 = off & 63;   // 64 B per tile row
  const size_t ga0 = (size_t)r0 * (HID * 2) + c0;
  const size_t ga1 = ga0 + (size_t)64 * (HID * 2);
  const int lb0 = wave * 512;               // LDS dest (elements); HW adds lane*16B
  const int lb1 = 2048 + wave * 512;

  f32x4 acc[4][4];
#pragma unroll
  for (int i = 0; i < 4; ++i)
#pragma unroll
    for (int j = 0; j < 4; ++j) acc[i][j] = f32x4{0.f, 0.f, 0.f, 0.f};

  auto stage = [&](int bufi, int k0) {
    const size_t kb = (size_t)k0 * 2;
    gll16(Ab + ga0 + kb, &Ash[bufi][lb0]);
    gll16(Ab + ga1 + kb, &Ash[bufi][lb1]);
    gll16(Bb + ga0 + kb, &Bsh[bufi][lb0]);
    gll16(Bb + ga1 + kb, &Bsh[bufi][lb1]);
  };
  auto compute = [&](int bufi) {
    s16x8 af[4], bfr[4];
#pragma unroll
    for (int i = 0; i < 4; ++i)
      af[i] = *(const s16x8*)(&Ash[bufi][(wr * 64 + i * 16 + l15) * 32 + quad * 8]);
#pragma unroll
    for (int j = 0; j < 4; ++j)
      bfr[j] = *(const s16x8*)(&Bsh[bufi][(wc * 64 + j * 16 + l15) * 32 + quad * 8]);
#pragma unroll
    for (int i = 0; i < 4; ++i)
#pragma unroll
      for (int j = 0; j < 4; ++j)
        acc[i][j] = __builtin_amdgcn_mfma_f32_16x16x32_bf16(af[i], bfr[j], acc[i][j], 0, 0, 0);
  };

  // prologue: tiles 0..3 in flight (16 outstanding/wave)
  stage(0, 0);
  stage(1, 32);
  stage(2, 64);
  stage(3, 96);
  int cur = 0, pf = 4;
  const int NT = HID / 32;                  // 32
  for (int t = 0; t < NT - 4; ++t) {
    WAITBAR(12);                            // tile t landed; t+1..t+3 stay in flight
    stage(pf, (t + 4) * 32);
    compute(cur);
    cur = (cur == 4) ? 0 : cur + 1;
    pf  = (pf  == 4) ? 0 : pf + 1;
  }
  WAITBAR(12); compute(cur); cur = (cur == 4) ? 0 : cur + 1;   // t = NT-4
  WAITBAR(8);  compute(cur); cur = (cur == 4) ? 0 : cur + 1;   // t = NT-3
  WAITBAR(4);  compute(cur); cur = (cur == 4) ? 0 : cur + 1;   // t = NT-2
  WAITBAR(0);  compute(cur);                                   // t = NT-1

  const int mat = bn >> 10;                  // 0=Q 1=K 2=V (128-col blocks never straddle)
  const int cb = (bn & 1023) + wc * 64;
  const int rbase = bm + wr * 64;
  if (mat == 2) {
    // V: f16, transposed [B,NH,D,T]; 4 consecutive t per lane = 8B store
#pragma unroll
    for (int j = 0; j < 4; ++j) {
      const int coln = cb + j * 16 + l15;
      const int head = coln >> 6, d = coln & 63;
      const float bb = bv[coln];
#pragma unroll
      for (int i = 0; i < 4; ++i) {
        const int row0 = rbase + i * 16 + quad * 4;
        const int bI = row0 >> 11, t0 = row0 & 2047;
        unsigned short o[4];
#pragma unroll
        for (int r = 0; r < 4; ++r) {
          _Float16 hv = (_Float16)(acc[i][j][r] + bb);
          o[r] = __builtin_bit_cast(unsigned short, hv);
        }
        *(s16x4*)(vto + ((size_t)((bI * NH + head) * HD + d)) * TSEQ + t0) = *(const s16x4*)o;
      }
    }
  } else {
    unsigned short* dst = (mat == 0) ? qo : ko;
#pragma unroll
    for (int j = 0; j < 4; ++j) {
      const int coln = cb + j * 16 + l15;
      const int head = coln >> 6, d = coln & 63;
      const float bb = (mat == 0) ? bq[coln] : bk[coln] * KSCALE;
#pragma unroll
      for (int i = 0; i < 4; ++i) {
#pragma unroll
        for (int r = 0; r < 4; ++r) {
          const int row = rbase + i * 16 + quad * 4 + r;
          const int bI = row >> 11, t = row & 2047;
          dst[(((size_t)(bI * NH + head) * TSEQ) + t) * HD + d] = f2bf(acc[i][j][r] + bb);
        }
      }
    }
  }
}

// ---------------- Output projection: 128x64 tile, same 5-ring structure ----------------
__global__ __launch_bounds__(256) void gemm_out(
    const unsigned short* __restrict__ ctx, const unsigned short* __restrict__ wo,
    const float* __restrict__ bo, const float* __restrict__ hres,
    float* __restrict__ outf) {
  __shared__ unsigned short Ash[5][128 * 32];   // 5 x 8 KB
  __shared__ unsigned short Bsh[5][64 * 32];    // 5 x 4 KB  (total 60 KB)
  const int tid = threadIdx.x, lane = tid & 63, wave = tid >> 6;
  const int l15 = lane & 15, quad = lane >> 4;
  const int wr = wave >> 1, wc = wave & 1;      // each wave: 64 rows x 32 cols
  const int bn = blockIdx.x * 64, bm = blockIdx.y * 128;
  const char* Ab = (const char*)(ctx + (size_t)bm * HID);
  const char* Bb = (const char*)(wo + (size_t)bn * HID);
  const int off = tid * 16;
  const int r0 = off >> 6, c0 = off & 63;
  const size_t ga0 = (size_t)r0 * (HID * 2) + c0;
  const size_t ga1 = ga0 + (size_t)64 * (HID * 2);
  const int lb0 = wave * 512, lb1 = 2048 + wave * 512;

  f32x4 acc[4][2];
#pragma unroll
  for (int i = 0; i < 4; ++i)
#pragma unroll
    for (int j = 0; j < 2; ++j) acc[i][j] = f32x4{0.f, 0.f, 0.f, 0.f};

  auto stage = [&](int bufi, int k0) {
    const size_t kb = (size_t)k0 * 2;
    gll16(Ab + ga0 + kb, &Ash[bufi][lb0]);
    gll16(Ab + ga1 + kb, &Ash[bufi][lb1]);
    gll16(Bb + ga0 + kb, &Bsh[bufi][lb0]);   // 64x32 B-tile = exactly one issue
  };
  auto compute = [&](int bufi) {
    s16x8 af[4], bfr[2];
#pragma unroll
    for (int i = 0; i < 4; ++i)
      af[i] = *(const s16x8*)(&Ash[bufi][(wr * 64 + i * 16 + l15) * 32 + quad * 8]);
#pragma unroll
    for (int j = 0; j < 2; ++j)
      bfr[j] = *(const s16x8*)(&Bsh[bufi][(wc * 32 + j * 16 + l15) * 32 + quad * 8]);
#pragma unroll
    for (int i = 0; i < 4; ++i)
#pragma unroll
      for (int j = 0; j < 2; ++j)
        acc[i][j] = __builtin_amdgcn_mfma_f32_16x16x32_bf16(af[i], bfr[j], acc[i][j], 0, 0, 0);
  };

  stage(0, 0);
  stage(1, 32);
  stage(2, 64);
  stage(3, 96);
  int cur = 0, pf = 4;
  const int NT = HID / 32;
  for (int t = 0; t < NT - 4; ++t) {
    WAITBAR(9);                             // 3 loads/tile: tile t home, 3 tiles in flight
    stage(pf, (t + 4) * 32);
    compute(cur);
    cur = (cur == 4) ? 0 : cur + 1;
    pf  = (pf  == 4) ? 0 : pf + 1;
  }
  WAITBAR(9); compute(cur); cur = (cur == 4) ? 0 : cur + 1;    // t = NT-4
  WAITBAR(6); compute(cur); cur = (cur == 4) ? 0 : cur + 1;    // t = NT-3
  WAITBAR(3); compute(cur); cur = (cur == 4) ? 0 : cur + 1;    // t = NT-2
  WAITBAR(0); compute(cur);                                    // t = NT-1

#pragma unroll
  for (int j = 0; j < 2; ++j) {
    const int col = bn + wc * 32 + j * 16 + l15;
    const float bb = bo[col];
#pragma unroll
    for (int i = 0; i < 4; ++i) {
#pragma unroll
      for (int r = 0; r < 4; ++r) {
        const int row = bm + wr * 64 + i * 16 + quad * 4 + r;
        const size_t o = (size_t)row * HID + col;
        outf[o] = acc[i][j][r] + bb + hres[o];
      }
    }
  }
}

// ---------------- Flash attention: S^T formulation, K-split by 1/2 ----------------
__global__ __launch_bounds__(256, 2) void attn_k(
    const unsigned short* __restrict__ qb, const unsigned short* __restrict__ kb,
    const unsigned short* __restrict__ vt, unsigned short* __restrict__ ctx,
    unsigned short* __restrict__ Opart, float* __restrict__ rsumP,
    int lsplit, int ntiles) {
  __shared__ unsigned short Ksh[64 * 72];   // bf16 [key][d]
  __shared__ unsigned short Vsh[64 * 72];   // f16  [d][key]

  const int tid = threadIdx.x, lane = tid & 63, wave = tid >> 6;
  const int l15 = lane & 15, quad = lane >> 4;
  const int z = blockIdx.z;
  const int b = z >> lsplit;
  const int part = z & ((1 << lsplit) - 1);
  const int h = blockIdx.y, qt = blockIdx.x;
  const size_t ho = ((size_t)(b * NH + h)) * TSEQ * HD;
  const unsigned short* Qh = qb + ho;
  const unsigned short* Kh = kb + ho;
  const unsigned short* Vh = vt + ho;
  const int q0 = qt * 128 + wave * 32;
  const int kt0 = part * ntiles;

  s16x8 qf[2][2];
#pragma unroll
  for (int s = 0; s < 2; ++s)
#pragma unroll
    for (int ks = 0; ks < 2; ++ks)
      qf[s][ks] = *(const s16x8*)(Qh + (size_t)(q0 + s * 16 + l15) * HD + ks * 32 + quad * 8);

  f32x4 accO[4][2];   // O^T: [d-strip n2][q-col s], lane=(d=quad*4+r, q=l15)
  float rsum[2];
#pragma unroll
  for (int n2 = 0; n2 < 4; ++n2)
#pragma unroll
    for (int s = 0; s < 2; ++s) accO[n2][s] = f32x4{0.f, 0.f, 0.f, 0.f};
  rsum[0] = rsum[1] = 0.f;

  const int sr = tid >> 3, sc = (tid & 7) * 8;
  s16x8 kreg[2], vreg[2];
#pragma unroll
  for (int hf = 0; hf < 2; ++hf) {
    kreg[hf] = *(const s16x8*)(Kh + (size_t)(kt0 * 64 + sr + hf * 32) * HD + sc);
    vreg[hf] = *(const s16x8*)(Vh + (size_t)(sr + hf * 32) * TSEQ + kt0 * 64 + sc);
  }

  for (int kt = 0; kt < ntiles; ++kt) {
    __syncthreads();
#pragma unroll
    for (int hf = 0; hf < 2; ++hf) {
      *(s16x8*)(Ksh + (sr + hf * 32) * 72 + sc) = kreg[hf];
      *(s16x8*)(Vsh + (sr + hf * 32) * 72 + sc) = vreg[hf];
    }
    __syncthreads();
    if (kt + 1 < ntiles) {
      const int k0n = (kt0 + kt + 1) * 64;
#pragma unroll
      for (int hf = 0; hf < 2; ++hf) {
        kreg[hf] = *(const s16x8*)(Kh + (size_t)(k0n + sr + hf * 32) * HD + sc);
        vreg[hf] = *(const s16x8*)(Vh + (size_t)(sr + hf * 32) * TSEQ + k0n + sc);
      }
    }

    f32x4 accS[2][4];
#pragma unroll
    for (int s = 0; s < 2; ++s)
#pragma unroll
      for (int n = 0; n < 4; ++n) accS[s][n] = f32x4{0.f, 0.f, 0.f, 0.f};
#pragma unroll
    for (int ks = 0; ks < 2; ++ks) {
#pragma unroll
      for (int n = 0; n < 4; ++n) {
        s16x8 kf = *(const s16x8*)(Ksh + (n * 16 + l15) * 72 + ks * 32 + quad * 8);
#pragma unroll
        for (int s = 0; s < 2; ++s)
          accS[s][n] = __builtin_amdgcn_mfma_f32_16x16x32_bf16(kf, qf[s][ks], accS[s][n], 0, 0, 0);
      }
    }

    // raw v_exp_f32 (R10-verified: libm exp2f's fixup was the VALU bottleneck)
    f16x4 pB[2][4];
#pragma unroll
    for (int s = 0; s < 2; ++s)
#pragma unroll
      for (int n = 0; n < 4; ++n) {
        float e0 = __builtin_amdgcn_exp2f(accS[s][n][0]);
        float e1 = __builtin_amdgcn_exp2f(accS[s][n][1]);
        float e2 = __builtin_amdgcn_exp2f(accS[s][n][2]);
        float e3 = __builtin_amdgcn_exp2f(accS[s][n][3]);
        rsum[s] += (e0 + e1) + (e2 + e3);
        f16x2 lo = __builtin_bit_cast(f16x2, __builtin_amdgcn_cvt_pkrtz(e0, e1));
        f16x2 hi = __builtin_bit_cast(f16x2, __builtin_amdgcn_cvt_pkrtz(e2, e3));
        pB[s][n] = f16x4{lo[0], lo[1], hi[0], hi[1]};
      }

#pragma unroll
    for (int n = 0; n < 4; ++n) {
#pragma unroll
      for (int n2 = 0; n2 < 4; ++n2) {
        f16x4 vA = *(const f16x4*)(Vsh + (n2 * 16 + l15) * 72 + n * 16 + quad * 4);
#pragma unroll
        for (int s = 0; s < 2; ++s)
          accO[n2][s] = __builtin_amdgcn_mfma_f32_16x16x16f16(vA, pB[s][n], accO[n2][s], 0, 0, 0);
      }
    }
  }

#pragma unroll
  for (int s = 0; s < 2; ++s) {
    float t = rsum[s];
    t += __shfl_xor(t, 16, 64);
    t += __shfl_xor(t, 32, 64);
    rsum[s] = t;
  }

  if (lsplit) {
    const int slot = (part * BATCH + b) * NH + h;
    const size_t ob = (size_t)slot * TSEQ * HD;
#pragma unroll
    for (int s = 0; s < 2; ++s) {
      const int t = q0 + s * 16 + l15;
#pragma unroll
      for (int n2 = 0; n2 < 4; ++n2) {
        const int d0 = n2 * 16 + quad * 4;
        unsigned short o[4];
#pragma unroll
        for (int r = 0; r < 4; ++r) o[r] = f2bf(accO[n2][s][r]);
        *(s16x4*)(Opart + ob + (size_t)t * HD + d0) = *(const s16x4*)o;
      }
    }
    if (quad == 0) {
      const size_t rb = (size_t)slot * TSEQ;
#pragma unroll
      for (int s = 0; s < 2; ++s)
        rsumP[rb + q0 + s * 16 + l15] = rsum[s];
    }
  } else {
#pragma unroll
    for (int s = 0; s < 2; ++s) {
      const int t = q0 + s * 16 + l15;
      const float inv = 1.f / rsum[s];
#pragma unroll
      for (int n2 = 0; n2 < 4; ++n2) {
        const int d0 = n2 * 16 + quad * 4;
        unsigned short o[4];
#pragma unroll
        for (int r = 0; r < 4; ++r) o[r] = f2bf(accO[n2][s][r] * inv);
        *(s16x4*)(ctx + ((size_t)(b * TSEQ + t)) * HID + h * HD + d0) = *(const s16x4*)o;
      }
    }
  }
}

// ---------------- combine K-split parts: ctx = sum(O_p)/sum(r_p), bf16 ----------------
__global__ __launch_bounds__(256) void combine_k(
    const unsigned short* __restrict__ Opart, const float* __restrict__ rsumP,
    unsigned short* __restrict__ ctx, int nparts) {
  const int gtid = blockIdx.x * 256 + threadIdx.x;  // 524288 total
  const int d = (gtid & 7) * 8;
  const int rem = gtid >> 3;
  const int t = rem & 2047;
  const int bh = rem >> 11;          // b*NH + h  (0..31)
  float acc[8] = {0, 0, 0, 0, 0, 0, 0, 0};
  float rs = 0.f;
  for (int p = 0; p < nparts; ++p) {
    const int slot = p * 32 + bh;
    s16x8 a = *(const s16x8*)(Opart + ((size_t)slot * TSEQ + t) * HD + d);
#pragma unroll
    for (int j = 0; j < 8; ++j) acc[j] += bf2f(((const unsigned short*)&a)[j]);
    rs += rsumP[(size_t)slot * TSEQ + t];
  }
  const float inv = 1.f / rs;
  unsigned short o[8];
#pragma unroll
  for (int j = 0; j < 8; ++j) o[j] = f2bf(acc[j] * inv);
  const int b = bh >> 4, h = bh & 15;
  *(s16x8*)(ctx + ((size_t)(b * TSEQ + t)) * HID + h * HD + d) = *(const s16x8*)o;
}

// ---------------- In-place LayerNorm over rows of 1024 ----------------
__global__ __launch_bounds__(256) void ln_k(float* __restrict__ io,
                                            const float* __restrict__ gamma,
                                            const float* __restrict__ beta) {
  const int row = blockIdx.x, tid = threadIdx.x;
  float x[4]; float s = 0.f, s2 = 0.f;
#pragma unroll
  for (int i = 0; i < 4; ++i) {
    x[i] = io[(size_t)row * HID + tid + i * 256];
    s += x[i]; s2 += x[i] * x[i];
  }
#pragma unroll
  for (int off = 1; off < 64; off <<= 1) {
    s  += __shfl_xor(s, off, 64);
    s2 += __shfl_xor(s2, off, 64);
  }
  __shared__ float red[8];
  const int wave = tid >> 6;
  if ((tid & 63) == 0) { red[wave] = s; red[wave + 4] = s2; }
  __syncthreads();
  s  = red[0] + red[1] + red[2] + red[3];
  s2 = red[4] + red[5] + red[6] + red[7];
  const float mean = s * (1.f / HID);
  const float var  = s2 * (1.f / HID) - mean * mean;
  const float rstd = rsqrtf(var + 1e-6f);
#pragma unroll
  for (int i = 0; i < 4; ++i) {
    const int col = tid + i * 256;
    io[(size_t)row * HID + col] = (x[i] - mean) * rstd * gamma[col] + beta[col];
  }
}

extern "C" void kernel_launch(void* const* d_in, const int* in_sizes, int n_in,
                              void* d_out, int out_size, void* d_ws, size_t ws_size,
                              hipStream_t stream) {
  const float* h    = (const float*)d_in[0];
  const float* Wq   = (const float*)d_in[1];
  const float* bq   = (const float*)d_in[2];
  const float* Wk   = (const float*)d_in[3];
  const float* bk   = (const float*)d_in[4];
  const float* Wv   = (const float*)d_in[5];
  const float* bv   = (const float*)d_in[6];
  const float* Wo   = (const float*)d_in[7];
  const float* bo   = (const float*)d_in[8];
  const float* gamma = (const float*)d_in[9];
  const float* beta  = (const float*)d_in[10];
  float* out = (float*)d_out;

  unsigned short* hb   = (unsigned short*)d_ws;   // bf16 h; dead after gemm_qkv -> reused as ctx
  unsigned short* wqb  = hb  + 4194304;           // 4 weights contiguous (Wq|Wk|Wv|Wo)
  unsigned short* wkb  = wqb + 1048576;
  unsigned short* wvb  = wkb + 1048576;
  unsigned short* wob  = wvb + 1048576;
  unsigned short* qb   = wob + 1048576;           // bf16 [B,NH,T,D]
  unsigned short* kb   = qb  + 4194304;
  unsigned short* vtf  = kb  + 4194304;           // f16 [B,NH,D,T], written by gemm_qkv directly
  unsigned short* Opart = vtf + 4194304;          // bf16 partials (2 parts x 8 MiB)
  unsigned short* ctxb = hb;                      // ctx aliases dead hb

  const size_t base = (size_t)(vtf + 4194304 - hb) * 2;  // bytes before Opart (40 MiB)
  int lsplit = 0;
  if (ws_size >= base + 2u * 8388608 + 2u * 262144) lsplit = 1;  // ~57 MiB
  const int nparts = 1 << lsplit;
  float* rsumP = (float*)(Opart + (size_t)nparts * 4194304);

  cast_all_k<<<8192, 256, 0, stream>>>(h, Wq, Wk, Wv, Wo, hb, wqb);
  gemm_qkv<<<dim3(24, 32), 256, 0, stream>>>(hb, wqb, bq, bk, bv, qb, kb, vtf);
  attn_k<<<dim3(TSEQ / 128, NH, BATCH << lsplit), 256, 0, stream>>>(
      qb, kb, vtf, ctxb, Opart, rsumP, lsplit, 32 >> lsplit);
  if (lsplit)
    combine_k<<<2048, 256, 0, stream>>>(Opart, rsumP, ctxb, nparts);
  gemm_out<<<dim3(16, 32), 256, 0, stream>>>(ctxb, wob, bo, h, out);
  ln_k<<<4096, 256, 0, stream>>>(out, gamma, beta);
}

// Round 5
// 217.841 us; speedup vs baseline: 1.0830x; 1.0158x over previous
//
#include <hip/hip_runtime.h>
#include <hip/hip_bf16.h>

#define NH   16
#define HD   64
#define HID  1024
#define TSEQ 2048
#define BATCH 2
#define KSCALE 0.18033688011112042f   // 0.125 * log2(e), folded into Wk/bk

typedef __attribute__((ext_vector_type(4))) float f32x4;
typedef __attribute__((ext_vector_type(8))) short s16x8;
typedef __attribute__((ext_vector_type(4))) short s16x4;
typedef __attribute__((ext_vector_type(8))) _Float16 f16x8;
typedef __attribute__((ext_vector_type(4))) _Float16 f16x4;
typedef __attribute__((ext_vector_type(2))) _Float16 f16x2;

__device__ __forceinline__ unsigned short f2bf(float f) {
  union { float f; unsigned int u; } v; v.f = f;
  unsigned int r = v.u + 0x7fffu + ((v.u >> 16) & 1u);
  return (unsigned short)(r >> 16);
}
__device__ __forceinline__ float bf2f(unsigned short b) {
  union { unsigned int u; float f; } v; v.u = ((unsigned int)b) << 16; return v.f;
}

// async global->LDS, 16B per lane; LDS dest must be wave-uniform base (+lane*16 by HW)
__device__ __forceinline__ void gll16(const void* g, void* l) {
  __builtin_amdgcn_global_load_lds(
      (const __attribute__((address_space(1))) unsigned int*)g,
      (__attribute__((address_space(3))) unsigned int*)l, 16, 0, 0);
}

// counted-vmcnt barrier: own-wave outstanding loads <= N, then collective barrier.
#define WAITBAR(N)                                                      \
  do {                                                                  \
    __builtin_amdgcn_sched_barrier(0);                                  \
    asm volatile("s_waitcnt vmcnt(" #N ")\n\ts_barrier" ::: "memory");  \
  } while (0)

// ---------------- one cast kernel: h + all 4 weights (Wk pre-scaled) ----------------
__global__ __launch_bounds__(256) void cast_all_k(
    const float* __restrict__ h,
    const float* __restrict__ w0, const float* __restrict__ w1,
    const float* __restrict__ w2, const float* __restrict__ w3,
    unsigned short* __restrict__ hb, unsigned short* __restrict__ wbase) {
  int i = blockIdx.x * 256 + threadIdx.x;  // 2097152 float4 total
  const float* src; unsigned short* dst; int idx; float sc = 1.f;
  if (i < 1048576) { src = h; dst = hb; idx = i; }
  else {
    int idx4 = i - 1048576;
    int w = idx4 >> 18;
    idx = idx4 & 262143;
    src = (w == 0) ? w0 : (w == 1) ? w1 : (w == 2) ? w2 : w3;
    dst = wbase + (size_t)(idx4 - idx) * 4;   // contiguous weight region
    if (w == 1) sc = KSCALE;
  }
  float4 v = ((const float4*)src)[idx];
  ushort4 o;
  o.x = f2bf(v.x * sc); o.y = f2bf(v.y * sc); o.z = f2bf(v.z * sc); o.w = f2bf(v.w * sc);
  ((ushort4*)dst)[idx] = o;
}

// ---------------- Fused QKV projection: one 4096x3072x1024 NT-GEMM ----------------
// 128x192 tile -> grid 512 = exactly 2 blocks/CU (no tail), ring-4 LDS (80 KB),
// prefetch distance 3, counted vmcnt (never 0 in main loop).
__global__ __launch_bounds__(256) void gemm_qkv(
    const unsigned short* __restrict__ hb,
    const unsigned short* __restrict__ wcat,   // [3072][1024] = Wq|Wk|Wv, Wk pre-scaled
    const float* __restrict__ bq, const float* __restrict__ bk, const float* __restrict__ bv,
    unsigned short* __restrict__ qo, unsigned short* __restrict__ ko,
    unsigned short* __restrict__ vto) {
  __shared__ unsigned short Ash[4][128 * 32];   // 4 x 8 KB
  __shared__ unsigned short Bsh[4][192 * 32];   // 4 x 12 KB  (total 80 KB -> 2 blocks/CU)
  const int tid = threadIdx.x, lane = tid & 63, wave = tid >> 6;
  const int l15 = lane & 15, quad = lane >> 4;
  const int wr = wave >> 1, wc = wave & 1;      // 2x2 waves, each 64x96 out
  const int bn = blockIdx.x * 192, bm = blockIdx.y * 128;
  const char* Ab = (const char*)(hb + (size_t)bm * HID);
  const char* Bb = (const char*)(wcat + (size_t)bn * HID);
  // staging: A tile [128 r][32 k] = 8 KB (2 issues), B tile [192 r][32 k] = 12 KB (3 issues)
  const int off = tid * 16;                 // byte offset within one 4 KB issue
  const int r0 = off >> 6, c0 = off & 63;   // 64 B per tile row
  const size_t ga0 = (size_t)r0 * (HID * 2) + c0;
  const size_t ga1 = ga0 + (size_t)64  * (HID * 2);
  const size_t gb2 = ga0 + (size_t)128 * (HID * 2);
  const int lb0 = wave * 512;               // LDS dest (elements); HW adds lane*16B
  const int lb1 = 2048 + wave * 512;
  const int lb2 = 4096 + wave * 512;

  f32x4 acc[4][6];
#pragma unroll
  for (int i = 0; i < 4; ++i)
#pragma unroll
    for (int j = 0; j < 6; ++j) acc[i][j] = f32x4{0.f, 0.f, 0.f, 0.f};

  auto stage = [&](int bufi, int k0) {      // 5 loads per thread per tile
    const size_t kb = (size_t)k0 * 2;
    gll16(Ab + ga0 + kb, &Ash[bufi][lb0]);
    gll16(Ab + ga1 + kb, &Ash[bufi][lb1]);
    gll16(Bb + ga0 + kb, &Bsh[bufi][lb0]);
    gll16(Bb + ga1 + kb, &Bsh[bufi][lb1]);
    gll16(Bb + gb2 + kb, &Bsh[bufi][lb2]);
  };
  auto compute = [&](int bufi) {
    s16x8 af[4], bfr[6];
#pragma unroll
    for (int i = 0; i < 4; ++i)
      af[i] = *(const s16x8*)(&Ash[bufi][(wr * 64 + i * 16 + l15) * 32 + quad * 8]);
#pragma unroll
    for (int j = 0; j < 6; ++j)
      bfr[j] = *(const s16x8*)(&Bsh[bufi][(wc * 96 + j * 16 + l15) * 32 + quad * 8]);
#pragma unroll
    for (int i = 0; i < 4; ++i)
#pragma unroll
      for (int j = 0; j < 6; ++j)
        acc[i][j] = __builtin_amdgcn_mfma_f32_16x16x32_bf16(af[i], bfr[j], acc[i][j], 0, 0, 0);
  };

  // prologue: tiles 0..2 in flight (15 outstanding/wave)
  stage(0, 0);
  stage(1, 32);
  stage(2, 64);
  int cur = 0, pf = 3;
  const int NT = HID / 32;                  // 32
  for (int t = 0; t < NT - 3; ++t) {        // t = 0..28
    WAITBAR(10);                            // tile t landed; t+1,t+2 stay in flight
    stage(pf, (t + 3) * 32);
    compute(cur);
    cur = (cur + 1) & 3;
    pf  = (pf + 1) & 3;
  }
  WAITBAR(10); compute(cur); cur = (cur + 1) & 3;   // t = NT-3
  WAITBAR(5);  compute(cur); cur = (cur + 1) & 3;   // t = NT-2
  WAITBAR(0);  compute(cur);                        // t = NT-1

  // epilogue: 16-col groups never straddle a 1024 boundary -> mat uniform per j
  const int rbase = bm + wr * 64;
#pragma unroll
  for (int j = 0; j < 6; ++j) {
    const int cg  = bn + wc * 96 + j * 16;  // group start (multiple of 16)
    const int mat = cg >> 10;               // 0=Q 1=K 2=V
    const int coln = (cg & 1023) + l15;     // column within matrix
    const int head = coln >> 6, d = coln & 63;
    if (mat == 2) {
      // V: f16, transposed [B,NH,D,T]; 4 consecutive t per lane = 8B store
      const float bb = bv[coln];
#pragma unroll
      for (int i = 0; i < 4; ++i) {
        const int row0 = rbase + i * 16 + quad * 4;
        const int bI = row0 >> 11, t0 = row0 & 2047;
        unsigned short o[4];
#pragma unroll
        for (int r = 0; r < 4; ++r) {
          _Float16 hv = (_Float16)(acc[i][j][r] + bb);
          o[r] = __builtin_bit_cast(unsigned short, hv);
        }
        *(s16x4*)(vto + ((size_t)((bI * NH + head) * HD + d)) * TSEQ + t0) = *(const s16x4*)o;
      }
    } else {
      unsigned short* dst = (mat == 0) ? qo : ko;
      const float bb = (mat == 0) ? bq[coln] : bk[coln] * KSCALE;
#pragma unroll
      for (int i = 0; i < 4; ++i) {
#pragma unroll
        for (int r = 0; r < 4; ++r) {
          const int row = rbase + i * 16 + quad * 4 + r;
          const int bI = row >> 11, t = row & 2047;
          dst[(((size_t)(bI * NH + head) * TSEQ) + t) * HD + d] = f2bf(acc[i][j][r] + bb);
        }
      }
    }
  }
}

// ---------------- Output projection: 128x64 tile, 5-ring depth-4 ----------------
__global__ __launch_bounds__(256) void gemm_out(
    const unsigned short* __restrict__ ctx, const unsigned short* __restrict__ wo,
    const float* __restrict__ bo, const float* __restrict__ hres,
    float* __restrict__ outf) {
  __shared__ unsigned short Ash[5][128 * 32];   // 5 x 8 KB
  __shared__ unsigned short Bsh[5][64 * 32];    // 5 x 4 KB  (total 60 KB)
  const int tid = threadIdx.x, lane = tid & 63, wave = tid >> 6;
  const int l15 = lane & 15, quad = lane >> 4;
  const int wr = wave >> 1, wc = wave & 1;      // each wave: 64 rows x 32 cols
  const int bn = blockIdx.x * 64, bm = blockIdx.y * 128;
  const char* Ab = (const char*)(ctx + (size_t)bm * HID);
  const char* Bb = (const char*)(wo + (size_t)bn * HID);
  const int off = tid * 16;
  const int r0 = off >> 6, c0 = off & 63;
  const size_t ga0 = (size_t)r0 * (HID * 2) + c0;
  const size_t ga1 = ga0 + (size_t)64 * (HID * 2);
  const int lb0 = wave * 512, lb1 = 2048 + wave * 512;

  f32x4 acc[4][2];
#pragma unroll
  for (int i = 0; i < 4; ++i)
#pragma unroll
    for (int j = 0; j < 2; ++j) acc[i][j] = f32x4{0.f, 0.f, 0.f, 0.f};

  auto stage = [&](int bufi, int k0) {
    const size_t kb = (size_t)k0 * 2;
    gll16(Ab + ga0 + kb, &Ash[bufi][lb0]);
    gll16(Ab + ga1 + kb, &Ash[bufi][lb1]);
    gll16(Bb + ga0 + kb, &Bsh[bufi][lb0]);   // 64x32 B-tile = exactly one issue
  };
  auto compute = [&](int bufi) {
    s16x8 af[4], bfr[2];
#pragma unroll
    for (int i = 0; i < 4; ++i)
      af[i] = *(const s16x8*)(&Ash[bufi][(wr * 64 + i * 16 + l15) * 32 + quad * 8]);
#pragma unroll
    for (int j = 0; j < 2; ++j)
      bfr[j] = *(const s16x8*)(&Bsh[bufi][(wc * 32 + j * 16 + l15) * 32 + quad * 8]);
#pragma unroll
    for (int i = 0; i < 4; ++i)
#pragma unroll
      for (int j = 0; j < 2; ++j)
        acc[i][j] = __builtin_amdgcn_mfma_f32_16x16x32_bf16(af[i], bfr[j], acc[i][j], 0, 0, 0);
  };

  stage(0, 0);
  stage(1, 32);
  stage(2, 64);
  stage(3, 96);
  int cur = 0, pf = 4;
  const int NT = HID / 32;
  for (int t = 0; t < NT - 4; ++t) {
    WAITBAR(9);                             // 3 loads/tile: tile t home, 3 tiles in flight
    stage(pf, (t + 4) * 32);
    compute(cur);
    cur = (cur == 4) ? 0 : cur + 1;
    pf  = (pf  == 4) ? 0 : pf + 1;
  }
  WAITBAR(9); compute(cur); cur = (cur == 4) ? 0 : cur + 1;    // t = NT-4
  WAITBAR(6); compute(cur); cur = (cur == 4) ? 0 : cur + 1;    // t = NT-3
  WAITBAR(3); compute(cur); cur = (cur == 4) ? 0 : cur + 1;    // t = NT-2
  WAITBAR(0); compute(cur);                                    // t = NT-1

#pragma unroll
  for (int j = 0; j < 2; ++j) {
    const int col = bn + wc * 32 + j * 16 + l15;
    const float bb = bo[col];
#pragma unroll
    for (int i = 0; i < 4; ++i) {
#pragma unroll
      for (int r = 0; r < 4; ++r) {
        const int row = bm + wr * 64 + i * 16 + quad * 4 + r;
        const size_t o = (size_t)row * HID + col;
        outf[o] = acc[i][j][r] + bb + hres[o];
      }
    }
  }
}

// ---------------- Flash attention: S^T formulation, K-split by 1/2/4 ----------------
__global__ __launch_bounds__(256, 2) void attn_k(
    const unsigned short* __restrict__ qb, const unsigned short* __restrict__ kb,
    const unsigned short* __restrict__ vt, unsigned short* __restrict__ ctx,
    unsigned short* __restrict__ Opart, float* __restrict__ rsumP,
    int lsplit, int ntiles) {
  __shared__ unsigned short Ksh[64 * 72];   // bf16 [key][d]
  __shared__ unsigned short Vsh[64 * 72];   // f16  [d][key]

  const int tid = threadIdx.x, lane = tid & 63, wave = tid >> 6;
  const int l15 = lane & 15, quad = lane >> 4;
  const int z = blockIdx.z;
  const int b = z >> lsplit;
  const int part = z & ((1 << lsplit) - 1);
  const int h = blockIdx.y, qt = blockIdx.x;
  const size_t ho = ((size_t)(b * NH + h)) * TSEQ * HD;
  const unsigned short* Qh = qb + ho;
  const unsigned short* Kh = kb + ho;
  const unsigned short* Vh = vt + ho;
  const int q0 = qt * 128 + wave * 32;
  const int kt0 = part * ntiles;

  s16x8 qf[2][2];
#pragma unroll
  for (int s = 0; s < 2; ++s)
#pragma unroll
    for (int ks = 0; ks < 2; ++ks)
      qf[s][ks] = *(const s16x8*)(Qh + (size_t)(q0 + s * 16 + l15) * HD + ks * 32 + quad * 8);

  f32x4 accO[4][2];   // O^T: [d-strip n2][q-col s], lane=(d=quad*4+r, q=l15)
  float rsum[2];
#pragma unroll
  for (int n2 = 0; n2 < 4; ++n2)
#pragma unroll
    for (int s = 0; s < 2; ++s) accO[n2][s] = f32x4{0.f, 0.f, 0.f, 0.f};
  rsum[0] = rsum[1] = 0.f;

  const int sr = tid >> 3, sc = (tid & 7) * 8;
  s16x8 kreg[2], vreg[2];
#pragma unroll
  for (int hf = 0; hf < 2; ++hf) {
    kreg[hf] = *(const s16x8*)(Kh + (size_t)(kt0 * 64 + sr + hf * 32) * HD + sc);
    vreg[hf] = *(const s16x8*)(Vh + (size_t)(sr + hf * 32) * TSEQ + kt0 * 64 + sc);
  }

  for (int kt = 0; kt < ntiles; ++kt) {
    __syncthreads();
#pragma unroll
    for (int hf = 0; hf < 2; ++hf) {
      *(s16x8*)(Ksh + (sr + hf * 32) * 72 + sc) = kreg[hf];
      *(s16x8*)(Vsh + (sr + hf * 32) * 72 + sc) = vreg[hf];
    }
    __syncthreads();
    if (kt + 1 < ntiles) {
      const int k0n = (kt0 + kt + 1) * 64;
#pragma unroll
      for (int hf = 0; hf < 2; ++hf) {
        kreg[hf] = *(const s16x8*)(Kh + (size_t)(k0n + sr + hf * 32) * HD + sc);
        vreg[hf] = *(const s16x8*)(Vh + (size_t)(sr + hf * 32) * TSEQ + k0n + sc);
      }
    }

    f32x4 accS[2][4];
#pragma unroll
    for (int s = 0; s < 2; ++s)
#pragma unroll
      for (int n = 0; n < 4; ++n) accS[s][n] = f32x4{0.f, 0.f, 0.f, 0.f};
#pragma unroll
    for (int ks = 0; ks < 2; ++ks) {
#pragma unroll
      for (int n = 0; n < 4; ++n) {
        s16x8 kf = *(const s16x8*)(Ksh + (n * 16 + l15) * 72 + ks * 32 + quad * 8);
#pragma unroll
        for (int s = 0; s < 2; ++s)
          accS[s][n] = __builtin_amdgcn_mfma_f32_16x16x32_bf16(kf, qf[s][ks], accS[s][n], 0, 0, 0);
      }
    }

    // raw v_exp_f32 (R10-verified: libm exp2f's fixup was the VALU bottleneck)
    f16x4 pB[2][4];
#pragma unroll
    for (int s = 0; s < 2; ++s)
#pragma unroll
      for (int n = 0; n < 4; ++n) {
        float e0 = __builtin_amdgcn_exp2f(accS[s][n][0]);
        float e1 = __builtin_amdgcn_exp2f(accS[s][n][1]);
        float e2 = __builtin_amdgcn_exp2f(accS[s][n][2]);
        float e3 = __builtin_amdgcn_exp2f(accS[s][n][3]);
        rsum[s] += (e0 + e1) + (e2 + e3);
        f16x2 lo = __builtin_bit_cast(f16x2, __builtin_amdgcn_cvt_pkrtz(e0, e1));
        f16x2 hi = __builtin_bit_cast(f16x2, __builtin_amdgcn_cvt_pkrtz(e2, e3));
        pB[s][n] = f16x4{lo[0], lo[1], hi[0], hi[1]};
      }

#pragma unroll
    for (int n = 0; n < 4; ++n) {
#pragma unroll
      for (int n2 = 0; n2 < 4; ++n2) {
        f16x4 vA = *(const f16x4*)(Vsh + (n2 * 16 + l15) * 72 + n * 16 + quad * 4);
#pragma unroll
        for (int s = 0; s < 2; ++s)
          accO[n2][s] = __builtin_amdgcn_mfma_f32_16x16x16f16(vA, pB[s][n], accO[n2][s], 0, 0, 0);
      }
    }
  }

#pragma unroll
  for (int s = 0; s < 2; ++s) {
    float t = rsum[s];
    t += __shfl_xor(t, 16, 64);
    t += __shfl_xor(t, 32, 64);
    rsum[s] = t;
  }

  if (lsplit) {
    const int slot = (part * BATCH + b) * NH + h;
    const size_t ob = (size_t)slot * TSEQ * HD;
#pragma unroll
    for (int s = 0; s < 2; ++s) {
      const int t = q0 + s * 16 + l15;
#pragma unroll
      for (int n2 = 0; n2 < 4; ++n2) {
        const int d0 = n2 * 16 + quad * 4;
        unsigned short o[4];
#pragma unroll
        for (int r = 0; r < 4; ++r) o[r] = f2bf(accO[n2][s][r]);
        *(s16x4*)(Opart + ob + (size_t)t * HD + d0) = *(const s16x4*)o;
      }
    }
    if (quad == 0) {
      const size_t rb = (size_t)slot * TSEQ;
#pragma unroll
      for (int s = 0; s < 2; ++s)
        rsumP[rb + q0 + s * 16 + l15] = rsum[s];
    }
  } else {
#pragma unroll
    for (int s = 0; s < 2; ++s) {
      const int t = q0 + s * 16 + l15;
      const float inv = 1.f / rsum[s];
#pragma unroll
      for (int n2 = 0; n2 < 4; ++n2) {
        const int d0 = n2 * 16 + quad * 4;
        unsigned short o[4];
#pragma unroll
        for (int r = 0; r < 4; ++r) o[r] = f2bf(accO[n2][s][r] * inv);
        *(s16x4*)(ctx + ((size_t)(b * TSEQ + t)) * HID + h * HD + d0) = *(const s16x4*)o;
      }
    }
  }
}

// ---------------- combine K-split parts: ctx = sum(O_p)/sum(r_p), bf16 ----------------
__global__ __launch_bounds__(256) void combine_k(
    const unsigned short* __restrict__ Opart, const float* __restrict__ rsumP,
    unsigned short* __restrict__ ctx, int nparts) {
  const int gtid = blockIdx.x * 256 + threadIdx.x;  // 524288 total
  const int d = (gtid & 7) * 8;
  const int rem = gtid >> 3;
  const int t = rem & 2047;
  const int bh = rem >> 11;          // b*NH + h  (0..31)
  float acc[8] = {0, 0, 0, 0, 0, 0, 0, 0};
  float rs = 0.f;
  for (int p = 0; p < nparts; ++p) {
    const int slot = p * 32 + bh;
    s16x8 a = *(const s16x8*)(Opart + ((size_t)slot * TSEQ + t) * HD + d);
#pragma unroll
    for (int j = 0; j < 8; ++j) acc[j] += bf2f(((const unsigned short*)&a)[j]);
    rs += rsumP[(size_t)slot * TSEQ + t];
  }
  const float inv = 1.f / rs;
  unsigned short o[8];
#pragma unroll
  for (int j = 0; j < 8; ++j) o[j] = f2bf(acc[j] * inv);
  const int b = bh >> 4, h = bh & 15;
  *(s16x8*)(ctx + ((size_t)(b * TSEQ + t)) * HID + h * HD + d) = *(const s16x8*)o;
}

// ---------------- In-place LayerNorm over rows of 1024 ----------------
__global__ __launch_bounds__(256) void ln_k(float* __restrict__ io,
                                            const float* __restrict__ gamma,
                                            const float* __restrict__ beta) {
  const int row = blockIdx.x, tid = threadIdx.x;
  float x[4]; float s = 0.f, s2 = 0.f;
#pragma unroll
  for (int i = 0; i < 4; ++i) {
    x[i] = io[(size_t)row * HID + tid + i * 256];
    s += x[i]; s2 += x[i] * x[i];
  }
#pragma unroll
  for (int off = 1; off < 64; off <<= 1) {
    s  += __shfl_xor(s, off, 64);
    s2 += __shfl_xor(s2, off, 64);
  }
  __shared__ float red[8];
  const int wave = tid >> 6;
  if ((tid & 63) == 0) { red[wave] = s; red[wave + 4] = s2; }
  __syncthreads();
  s  = red[0] + red[1] + red[2] + red[3];
  s2 = red[4] + red[5] + red[6] + red[7];
  const float mean = s * (1.f / HID);
  const float var  = s2 * (1.f / HID) - mean * mean;
  const float rstd = rsqrtf(var + 1e-6f);
#pragma unroll
  for (int i = 0; i < 4; ++i) {
    const int col = tid + i * 256;
    io[(size_t)row * HID + col] = (x[i] - mean) * rstd * gamma[col] + beta[col];
  }
}

extern "C" void kernel_launch(void* const* d_in, const int* in_sizes, int n_in,
                              void* d_out, int out_size, void* d_ws, size_t ws_size,
                              hipStream_t stream) {
  const float* h    = (const float*)d_in[0];
  const float* Wq   = (const float*)d_in[1];
  const float* bq   = (const float*)d_in[2];
  const float* Wk   = (const float*)d_in[3];
  const float* bk   = (const float*)d_in[4];
  const float* Wv   = (const float*)d_in[5];
  const float* bv   = (const float*)d_in[6];
  const float* Wo   = (const float*)d_in[7];
  const float* bo   = (const float*)d_in[8];
  const float* gamma = (const float*)d_in[9];
  const float* beta  = (const float*)d_in[10];
  float* out = (float*)d_out;

  unsigned short* hb   = (unsigned short*)d_ws;   // bf16 h; dead after gemm_qkv -> reused as ctx
  unsigned short* wqb  = hb  + 4194304;           // 4 weights contiguous (Wq|Wk|Wv|Wo)
  unsigned short* wkb  = wqb + 1048576;
  unsigned short* wvb  = wkb + 1048576;
  unsigned short* wob  = wvb + 1048576;
  unsigned short* qb   = wob + 1048576;           // bf16 [B,NH,T,D]
  unsigned short* kb   = qb  + 4194304;
  unsigned short* vtf  = kb  + 4194304;           // f16 [B,NH,D,T], written by gemm_qkv directly
  unsigned short* Opart = vtf + 4194304;          // bf16 partials (nparts x 8 MiB)
  unsigned short* ctxb = hb;                      // ctx aliases dead hb

  const size_t base = (size_t)(vtf + 4194304 - hb) * 2;  // bytes before Opart (40 MiB)
  int lsplit = 0;
  if (ws_size >= base + 4u * 8388608 + 4u * 262144) lsplit = 2;        // ~73 MiB
  else if (ws_size >= base + 2u * 8388608 + 2u * 262144) lsplit = 1;   // ~57 MiB
  const int nparts = 1 << lsplit;
  float* rsumP = (float*)(Opart + (size_t)nparts * 4194304);

  cast_all_k<<<8192, 256, 0, stream>>>(h, Wq, Wk, Wv, Wo, hb, wqb);
  gemm_qkv<<<dim3(16, 32), 256, 0, stream>>>(hb, wqb, bq, bk, bv, qb, kb, vtf);
  attn_k<<<dim3(TSEQ / 128, NH, BATCH << lsplit), 256, 0, stream>>>(
      qb, kb, vtf, ctxb, Opart, rsumP, lsplit, 32 >> lsplit);
  if (lsplit)
    combine_k<<<2048, 256, 0, stream>>>(Opart, rsumP, ctxb, nparts);
  gemm_out<<<dim3(16, 32), 256, 0, stream>>>(ctxb, wob, bo, h, out);
  ln_k<<<4096, 256, 0, stream>>>(out, gamma, beta);
}

// Round 6
// 209.546 us; speedup vs baseline: 1.1259x; 1.0396x over previous
//
#include <hip/hip_runtime.h>
#include <hip/hip_bf16.h>

#define NH   16
#define HD   64
#define HID  1024
#define TSEQ 2048
#define BATCH 2
#define KSCALE 0.18033688011112042f   // 0.125 * log2(e), folded into Wk/bk

typedef __attribute__((ext_vector_type(4))) float f32x4;
typedef __attribute__((ext_vector_type(8))) short s16x8;
typedef __attribute__((ext_vector_type(4))) short s16x4;
typedef __attribute__((ext_vector_type(8))) _Float16 f16x8;
typedef __attribute__((ext_vector_type(4))) _Float16 f16x4;
typedef __attribute__((ext_vector_type(2))) _Float16 f16x2;

__device__ __forceinline__ unsigned short f2bf(float f) {
  union { float f; unsigned int u; } v; v.f = f;
  unsigned int r = v.u + 0x7fffu + ((v.u >> 16) & 1u);
  return (unsigned short)(r >> 16);
}
__device__ __forceinline__ float bf2f(unsigned short b) {
  union { unsigned int u; float f; } v; v.u = ((unsigned int)b) << 16; return v.f;
}

// async global->LDS, 16B per lane; LDS dest must be wave-uniform base (+lane*16 by HW)
__device__ __forceinline__ void gll16(const void* g, void* l) {
  __builtin_amdgcn_global_load_lds(
      (const __attribute__((address_space(1))) unsigned int*)g,
      (__attribute__((address_space(3))) unsigned int*)l, 16, 0, 0);
}

// counted-vmcnt barrier: own-wave outstanding loads <= N, then collective barrier.
#define WAITBAR(N)                                                      \
  do {                                                                  \
    __builtin_amdgcn_sched_barrier(0);                                  \
    asm volatile("s_waitcnt vmcnt(" #N ")\n\ts_barrier" ::: "memory");  \
  } while (0)

// ---------------- one cast kernel: h + all 4 weights (Wk pre-scaled) ----------------
__global__ __launch_bounds__(256) void cast_all_k(
    const float* __restrict__ h,
    const float* __restrict__ w0, const float* __restrict__ w1,
    const float* __restrict__ w2, const float* __restrict__ w3,
    unsigned short* __restrict__ hb, unsigned short* __restrict__ wbase) {
  int i = blockIdx.x * 256 + threadIdx.x;  // 2097152 float4 total
  const float* src; unsigned short* dst; int idx; float sc = 1.f;
  if (i < 1048576) { src = h; dst = hb; idx = i; }
  else {
    int idx4 = i - 1048576;
    int w = idx4 >> 18;
    idx = idx4 & 262143;
    src = (w == 0) ? w0 : (w == 1) ? w1 : (w == 2) ? w2 : w3;
    dst = wbase + (size_t)(idx4 - idx) * 4;   // contiguous weight region
    if (w == 1) sc = KSCALE;
  }
  float4 v = ((const float4*)src)[idx];
  ushort4 o;
  o.x = f2bf(v.x * sc); o.y = f2bf(v.y * sc); o.z = f2bf(v.z * sc); o.w = f2bf(v.w * sc);
  ((ushort4*)dst)[idx] = o;
}

// ---------------- Fused QKV projection: one 4096x3072x1024 NT-GEMM ----------------
// 128x192 tile -> grid 512 = exactly 2 blocks/CU (no tail), ring-4 LDS (80 KB),
// prefetch distance 3, counted vmcnt (never 0 in main loop).
__global__ __launch_bounds__(256) void gemm_qkv(
    const unsigned short* __restrict__ hb,
    const unsigned short* __restrict__ wcat,   // [3072][1024] = Wq|Wk|Wv, Wk pre-scaled
    const float* __restrict__ bq, const float* __restrict__ bk, const float* __restrict__ bv,
    unsigned short* __restrict__ qo, unsigned short* __restrict__ ko,
    unsigned short* __restrict__ vto) {
  __shared__ unsigned short Ash[4][128 * 32];   // 4 x 8 KB
  __shared__ unsigned short Bsh[4][192 * 32];   // 4 x 12 KB  (total 80 KB -> 2 blocks/CU)
  const int tid = threadIdx.x, lane = tid & 63, wave = tid >> 6;
  const int l15 = lane & 15, quad = lane >> 4;
  const int wr = wave >> 1, wc = wave & 1;      // 2x2 waves, each 64x96 out
  const int bn = blockIdx.x * 192, bm = blockIdx.y * 128;
  const char* Ab = (const char*)(hb + (size_t)bm * HID);
  const char* Bb = (const char*)(wcat + (size_t)bn * HID);
  // staging: A tile [128 r][32 k] = 8 KB (2 issues), B tile [192 r][32 k] = 12 KB (3 issues)
  const int off = tid * 16;                 // byte offset within one 4 KB issue
  const int r0 = off >> 6, c0 = off & 63;   // 64 B per tile row
  const size_t ga0 = (size_t)r0 * (HID * 2) + c0;
  const size_t ga1 = ga0 + (size_t)64  * (HID * 2);
  const size_t gb2 = ga0 + (size_t)128 * (HID * 2);
  const int lb0 = wave * 512;               // LDS dest (elements); HW adds lane*16B
  const int lb1 = 2048 + wave * 512;
  const int lb2 = 4096 + wave * 512;

  f32x4 acc[4][6];
#pragma unroll
  for (int i = 0; i < 4; ++i)
#pragma unroll
    for (int j = 0; j < 6; ++j) acc[i][j] = f32x4{0.f, 0.f, 0.f, 0.f};

  auto stage = [&](int bufi, int k0) {      // 5 loads per thread per tile
    const size_t kb = (size_t)k0 * 2;
    gll16(Ab + ga0 + kb, &Ash[bufi][lb0]);
    gll16(Ab + ga1 + kb, &Ash[bufi][lb1]);
    gll16(Bb + ga0 + kb, &Bsh[bufi][lb0]);
    gll16(Bb + ga1 + kb, &Bsh[bufi][lb1]);
    gll16(Bb + gb2 + kb, &Bsh[bufi][lb2]);
  };
  auto compute = [&](int bufi) {
    s16x8 af[4], bfr[6];
#pragma unroll
    for (int i = 0; i < 4; ++i)
      af[i] = *(const s16x8*)(&Ash[bufi][(wr * 64 + i * 16 + l15) * 32 + quad * 8]);
#pragma unroll
    for (int j = 0; j < 6; ++j)
      bfr[j] = *(const s16x8*)(&Bsh[bufi][(wc * 96 + j * 16 + l15) * 32 + quad * 8]);
#pragma unroll
    for (int i = 0; i < 4; ++i)
#pragma unroll
      for (int j = 0; j < 6; ++j)
        acc[i][j] = __builtin_amdgcn_mfma_f32_16x16x32_bf16(af[i], bfr[j], acc[i][j], 0, 0, 0);
  };

  // prologue: tiles 0..2 in flight (15 outstanding/wave)
  stage(0, 0);
  stage(1, 32);
  stage(2, 64);
  int cur = 0, pf = 3;
  const int NT = HID / 32;                  // 32
  for (int t = 0; t < NT - 3; ++t) {        // t = 0..28
    WAITBAR(10);                            // tile t landed; t+1,t+2 stay in flight
    stage(pf, (t + 3) * 32);
    compute(cur);
    cur = (cur + 1) & 3;
    pf  = (pf + 1) & 3;
  }
  WAITBAR(10); compute(cur); cur = (cur + 1) & 3;   // t = NT-3
  WAITBAR(5);  compute(cur); cur = (cur + 1) & 3;   // t = NT-2
  WAITBAR(0);  compute(cur);                        // t = NT-1

  // epilogue: 16-col groups never straddle a 1024 boundary -> mat uniform per j
  const int rbase = bm + wr * 64;
#pragma unroll
  for (int j = 0; j < 6; ++j) {
    const int cg  = bn + wc * 96 + j * 16;  // group start (multiple of 16)
    const int mat = cg >> 10;               // 0=Q 1=K 2=V
    const int coln = (cg & 1023) + l15;     // column within matrix
    const int head = coln >> 6, d = coln & 63;
    if (mat == 2) {
      // V: f16, transposed [B,NH,D,T]; 4 consecutive t per lane = 8B store
      const float bb = bv[coln];
#pragma unroll
      for (int i = 0; i < 4; ++i) {
        const int row0 = rbase + i * 16 + quad * 4;
        const int bI = row0 >> 11, t0 = row0 & 2047;
        unsigned short o[4];
#pragma unroll
        for (int r = 0; r < 4; ++r) {
          _Float16 hv = (_Float16)(acc[i][j][r] + bb);
          o[r] = __builtin_bit_cast(unsigned short, hv);
        }
        *(s16x4*)(vto + ((size_t)((bI * NH + head) * HD + d)) * TSEQ + t0) = *(const s16x4*)o;
      }
    } else {
      unsigned short* dst = (mat == 0) ? qo : ko;
      const float bb = (mat == 0) ? bq[coln] : bk[coln] * KSCALE;
#pragma unroll
      for (int i = 0; i < 4; ++i) {
#pragma unroll
        for (int r = 0; r < 4; ++r) {
          const int row = rbase + i * 16 + quad * 4 + r;
          const int bI = row >> 11, t = row & 2047;
          dst[(((size_t)(bI * NH + head) * TSEQ) + t) * HD + d] = f2bf(acc[i][j][r] + bb);
        }
      }
    }
  }
}

// ---------------- Output projection: 128x64 tile, 5-ring depth-4 ----------------
__global__ __launch_bounds__(256) void gemm_out(
    const unsigned short* __restrict__ ctx, const unsigned short* __restrict__ wo,
    const float* __restrict__ bo, const float* __restrict__ hres,
    float* __restrict__ outf) {
  __shared__ unsigned short Ash[5][128 * 32];   // 5 x 8 KB
  __shared__ unsigned short Bsh[5][64 * 32];    // 5 x 4 KB  (total 60 KB)
  const int tid = threadIdx.x, lane = tid & 63, wave = tid >> 6;
  const int l15 = lane & 15, quad = lane >> 4;
  const int wr = wave >> 1, wc = wave & 1;      // each wave: 64 rows x 32 cols
  const int bn = blockIdx.x * 64, bm = blockIdx.y * 128;
  const char* Ab = (const char*)(ctx + (size_t)bm * HID);
  const char* Bb = (const char*)(wo + (size_t)bn * HID);
  const int off = tid * 16;
  const int r0 = off >> 6, c0 = off & 63;
  const size_t ga0 = (size_t)r0 * (HID * 2) + c0;
  const size_t ga1 = ga0 + (size_t)64 * (HID * 2);
  const int lb0 = wave * 512, lb1 = 2048 + wave * 512;

  f32x4 acc[4][2];
#pragma unroll
  for (int i = 0; i < 4; ++i)
#pragma unroll
    for (int j = 0; j < 2; ++j) acc[i][j] = f32x4{0.f, 0.f, 0.f, 0.f};

  auto stage = [&](int bufi, int k0) {
    const size_t kb = (size_t)k0 * 2;
    gll16(Ab + ga0 + kb, &Ash[bufi][lb0]);
    gll16(Ab + ga1 + kb, &Ash[bufi][lb1]);
    gll16(Bb + ga0 + kb, &Bsh[bufi][lb0]);   // 64x32 B-tile = exactly one issue
  };
  auto compute = [&](int bufi) {
    s16x8 af[4], bfr[2];
#pragma unroll
    for (int i = 0; i < 4; ++i)
      af[i] = *(const s16x8*)(&Ash[bufi][(wr * 64 + i * 16 + l15) * 32 + quad * 8]);
#pragma unroll
    for (int j = 0; j < 2; ++j)
      bfr[j] = *(const s16x8*)(&Bsh[bufi][(wc * 32 + j * 16 + l15) * 32 + quad * 8]);
#pragma unroll
    for (int i = 0; i < 4; ++i)
#pragma unroll
      for (int j = 0; j < 2; ++j)
        acc[i][j] = __builtin_amdgcn_mfma_f32_16x16x32_bf16(af[i], bfr[j], acc[i][j], 0, 0, 0);
  };

  stage(0, 0);
  stage(1, 32);
  stage(2, 64);
  stage(3, 96);
  int cur = 0, pf = 4;
  const int NT = HID / 32;
  for (int t = 0; t < NT - 4; ++t) {
    WAITBAR(9);                             // 3 loads/tile: tile t home, 3 tiles in flight
    stage(pf, (t + 4) * 32);
    compute(cur);
    cur = (cur == 4) ? 0 : cur + 1;
    pf  = (pf  == 4) ? 0 : pf + 1;
  }
  WAITBAR(9); compute(cur); cur = (cur == 4) ? 0 : cur + 1;    // t = NT-4
  WAITBAR(6); compute(cur); cur = (cur == 4) ? 0 : cur + 1;    // t = NT-3
  WAITBAR(3); compute(cur); cur = (cur == 4) ? 0 : cur + 1;    // t = NT-2
  WAITBAR(0); compute(cur);                                    // t = NT-1

#pragma unroll
  for (int j = 0; j < 2; ++j) {
    const int col = bn + wc * 32 + j * 16 + l15;
    const float bb = bo[col];
#pragma unroll
    for (int i = 0; i < 4; ++i) {
#pragma unroll
      for (int r = 0; r < 4; ++r) {
        const int row = bm + wr * 64 + i * 16 + quad * 4 + r;
        const size_t o = (size_t)row * HID + col;
        outf[o] = acc[i][j][r] + bb + hres[o];
      }
    }
  }
}

// ---------------- Flash attention: S^T formulation, K-split by 1/2 ----------------
// PV upgraded to full-rate mfma_f32_16x16x32_f16: V stored key-permuted in LDS
// (p = kk*32 + q*8 + n*4 + r for key = n*16 + q*4 + r within 32-group kk) so the
// K=32 B-fragment is the lane-local concat {pB[s][2kk], pB[s][2kk+1]} - no shuffles.
__global__ __launch_bounds__(256, 2) void attn_k(
    const unsigned short* __restrict__ qb, const unsigned short* __restrict__ kb,
    const unsigned short* __restrict__ vt, unsigned short* __restrict__ ctx,
    unsigned short* __restrict__ Opart, float* __restrict__ rsumP,
    int lsplit, int ntiles) {
  __shared__ unsigned short Ksh[64 * 72];   // bf16 [key][d]
  __shared__ unsigned short Vsh[64 * 72];   // f16  [d][key-permuted]

  const int tid = threadIdx.x, lane = tid & 63, wave = tid >> 6;
  const int l15 = lane & 15, quad = lane >> 4;
  const int z = blockIdx.z;
  const int b = z >> lsplit;
  const int part = z & ((1 << lsplit) - 1);
  const int h = blockIdx.y, qt = blockIdx.x;
  const size_t ho = ((size_t)(b * NH + h)) * TSEQ * HD;
  const unsigned short* Qh = qb + ho;
  const unsigned short* Kh = kb + ho;
  const unsigned short* Vh = vt + ho;
  const int q0 = qt * 128 + wave * 32;
  const int kt0 = part * ntiles;

  s16x8 qf[2][2];
#pragma unroll
  for (int s = 0; s < 2; ++s)
#pragma unroll
    for (int ks = 0; ks < 2; ++ks)
      qf[s][ks] = *(const s16x8*)(Qh + (size_t)(q0 + s * 16 + l15) * HD + ks * 32 + quad * 8);

  f32x4 accO[4][2];   // O^T: [d-strip n2][q-col s], lane=(d=quad*4+r, q=l15)
  float rsum[2];
#pragma unroll
  for (int n2 = 0; n2 < 4; ++n2)
#pragma unroll
    for (int s = 0; s < 2; ++s) accO[n2][s] = f32x4{0.f, 0.f, 0.f, 0.f};
  rsum[0] = rsum[1] = 0.f;

  const int sr = tid >> 3, sc = (tid & 7) * 8;
  // V permuted write base: c = key-chunk index 0..7, keys 8c..8c+7 ->
  // two 4-key runs at vwb and vwb+8 (verified element-wise)
  const int c = tid & 7;
  const int vwb = (c >> 2) * 32 + (c & 1) * 16 + ((c & 3) >> 1) * 4;
  s16x8 kreg[2], vreg[2];
#pragma unroll
  for (int hf = 0; hf < 2; ++hf) {
    kreg[hf] = *(const s16x8*)(Kh + (size_t)(kt0 * 64 + sr + hf * 32) * HD + sc);
    vreg[hf] = *(const s16x8*)(Vh + (size_t)(sr + hf * 32) * TSEQ + kt0 * 64 + sc);
  }

  for (int kt = 0; kt < ntiles; ++kt) {
    __syncthreads();
#pragma unroll
    for (int hf = 0; hf < 2; ++hf) {
      *(s16x8*)(Ksh + (sr + hf * 32) * 72 + sc) = kreg[hf];
      const s16x4* vh = (const s16x4*)&vreg[hf];
      *(s16x4*)(Vsh + (sr + hf * 32) * 72 + vwb)     = vh[0];
      *(s16x4*)(Vsh + (sr + hf * 32) * 72 + vwb + 8) = vh[1];
    }
    __syncthreads();
    if (kt + 1 < ntiles) {
      const int k0n = (kt0 + kt + 1) * 64;
#pragma unroll
      for (int hf = 0; hf < 2; ++hf) {
        kreg[hf] = *(const s16x8*)(Kh + (size_t)(k0n + sr + hf * 32) * HD + sc);
        vreg[hf] = *(const s16x8*)(Vh + (size_t)(sr + hf * 32) * TSEQ + k0n + sc);
      }
    }

    f32x4 accS[2][4];
#pragma unroll
    for (int s = 0; s < 2; ++s)
#pragma unroll
      for (int n = 0; n < 4; ++n) accS[s][n] = f32x4{0.f, 0.f, 0.f, 0.f};
#pragma unroll
    for (int ks = 0; ks < 2; ++ks) {
#pragma unroll
      for (int n = 0; n < 4; ++n) {
        s16x8 kf = *(const s16x8*)(Ksh + (n * 16 + l15) * 72 + ks * 32 + quad * 8);
#pragma unroll
        for (int s = 0; s < 2; ++s)
          accS[s][n] = __builtin_amdgcn_mfma_f32_16x16x32_bf16(kf, qf[s][ks], accS[s][n], 0, 0, 0);
      }
    }

    // raw v_exp_f32 (R10-verified: libm exp2f's fixup was the VALU bottleneck)
    f16x4 pB[2][4];
#pragma unroll
    for (int s = 0; s < 2; ++s)
#pragma unroll
      for (int n = 0; n < 4; ++n) {
        float e0 = __builtin_amdgcn_exp2f(accS[s][n][0]);
        float e1 = __builtin_amdgcn_exp2f(accS[s][n][1]);
        float e2 = __builtin_amdgcn_exp2f(accS[s][n][2]);
        float e3 = __builtin_amdgcn_exp2f(accS[s][n][3]);
        rsum[s] += (e0 + e1) + (e2 + e3);
        f16x2 lo = __builtin_bit_cast(f16x2, __builtin_amdgcn_cvt_pkrtz(e0, e1));
        f16x2 hi = __builtin_bit_cast(f16x2, __builtin_amdgcn_cvt_pkrtz(e2, e3));
        pB[s][n] = f16x4{lo[0], lo[1], hi[0], hi[1]};
      }

    // PV: K=32 full-rate f16 MFMA; B = lane-local concat of two 16-key slots
#pragma unroll
    for (int kk = 0; kk < 2; ++kk) {
      union { f16x4 h[2]; f16x8 v8; } u0, u1;
      u0.h[0] = pB[0][2 * kk]; u0.h[1] = pB[0][2 * kk + 1];
      u1.h[0] = pB[1][2 * kk]; u1.h[1] = pB[1][2 * kk + 1];
#pragma unroll
      for (int n2 = 0; n2 < 4; ++n2) {
        f16x8 vA = *(const f16x8*)(Vsh + (n2 * 16 + l15) * 72 + kk * 32 + quad * 8);
        accO[n2][0] = __builtin_amdgcn_mfma_f32_16x16x32_f16(vA, u0.v8, accO[n2][0], 0, 0, 0);
        accO[n2][1] = __builtin_amdgcn_mfma_f32_16x16x32_f16(vA, u1.v8, accO[n2][1], 0, 0, 0);
      }
    }
  }

#pragma unroll
  for (int s = 0; s < 2; ++s) {
    float t = rsum[s];
    t += __shfl_xor(t, 16, 64);
    t += __shfl_xor(t, 32, 64);
    rsum[s] = t;
  }

  if (lsplit) {
    const int slot = (part * BATCH + b) * NH + h;
    const size_t ob = (size_t)slot * TSEQ * HD;
#pragma unroll
    for (int s = 0; s < 2; ++s) {
      const int t = q0 + s * 16 + l15;
#pragma unroll
      for (int n2 = 0; n2 < 4; ++n2) {
        const int d0 = n2 * 16 + quad * 4;
        unsigned short o[4];
#pragma unroll
        for (int r = 0; r < 4; ++r) o[r] = f2bf(accO[n2][s][r]);
        *(s16x4*)(Opart + ob + (size_t)t * HD + d0) = *(const s16x4*)o;
      }
    }
    if (quad == 0) {
      const size_t rb = (size_t)slot * TSEQ;
#pragma unroll
      for (int s = 0; s < 2; ++s)
        rsumP[rb + q0 + s * 16 + l15] = rsum[s];
    }
  } else {
#pragma unroll
    for (int s = 0; s < 2; ++s) {
      const int t = q0 + s * 16 + l15;
      const float inv = 1.f / rsum[s];
#pragma unroll
      for (int n2 = 0; n2 < 4; ++n2) {
        const int d0 = n2 * 16 + quad * 4;
        unsigned short o[4];
#pragma unroll
        for (int r = 0; r < 4; ++r) o[r] = f2bf(accO[n2][s][r] * inv);
        *(s16x4*)(ctx + ((size_t)(b * TSEQ + t)) * HID + h * HD + d0) = *(const s16x4*)o;
      }
    }
  }
}

// ---------------- combine K-split parts: ctx = sum(O_p)/sum(r_p), bf16 ----------------
__global__ __launch_bounds__(256) void combine_k(
    const unsigned short* __restrict__ Opart, const float* __restrict__ rsumP,
    unsigned short* __restrict__ ctx, int nparts) {
  const int gtid = blockIdx.x * 256 + threadIdx.x;  // 524288 total
  const int d = (gtid & 7) * 8;
  const int rem = gtid >> 3;
  const int t = rem & 2047;
  const int bh = rem >> 11;          // b*NH + h  (0..31)
  float acc[8] = {0, 0, 0, 0, 0, 0, 0, 0};
  float rs = 0.f;
  for (int p = 0; p < nparts; ++p) {
    const int slot = p * 32 + bh;
    s16x8 a = *(const s16x8*)(Opart + ((size_t)slot * TSEQ + t) * HD + d);
#pragma unroll
    for (int j = 0; j < 8; ++j) acc[j] += bf2f(((const unsigned short*)&a)[j]);
    rs += rsumP[(size_t)slot * TSEQ + t];
  }
  const float inv = 1.f / rs;
  unsigned short o[8];
#pragma unroll
  for (int j = 0; j < 8; ++j) o[j] = f2bf(acc[j] * inv);
  const int b = bh >> 4, h = bh & 15;
  *(s16x8*)(ctx + ((size_t)(b * TSEQ + t)) * HID + h * HD + d) = *(const s16x8*)o;
}

// ---------------- In-place LayerNorm over rows of 1024 ----------------
__global__ __launch_bounds__(256) void ln_k(float* __restrict__ io,
                                            const float* __restrict__ gamma,
                                            const float* __restrict__ beta) {
  const int row = blockIdx.x, tid = threadIdx.x;
  float x[4]; float s = 0.f, s2 = 0.f;
#pragma unroll
  for (int i = 0; i < 4; ++i) {
    x[i] = io[(size_t)row * HID + tid + i * 256];
    s += x[i]; s2 += x[i] * x[i];
  }
#pragma unroll
  for (int off = 1; off < 64; off <<= 1) {
    s  += __shfl_xor(s, off, 64);
    s2 += __shfl_xor(s2, off, 64);
  }
  __shared__ float red[8];
  const int wave = tid >> 6;
  if ((tid & 63) == 0) { red[wave] = s; red[wave + 4] = s2; }
  __syncthreads();
  s  = red[0] + red[1] + red[2] + red[3];
  s2 = red[4] + red[5] + red[6] + red[7];
  const float mean = s * (1.f / HID);
  const float var  = s2 * (1.f / HID) - mean * mean;
  const float rstd = rsqrtf(var + 1e-6f);
#pragma unroll
  for (int i = 0; i < 4; ++i) {
    const int col = tid + i * 256;
    io[(size_t)row * HID + col] = (x[i] - mean) * rstd * gamma[col] + beta[col];
  }
}

extern "C" void kernel_launch(void* const* d_in, const int* in_sizes, int n_in,
                              void* d_out, int out_size, void* d_ws, size_t ws_size,
                              hipStream_t stream) {
  const float* h    = (const float*)d_in[0];
  const float* Wq   = (const float*)d_in[1];
  const float* bq   = (const float*)d_in[2];
  const float* Wk   = (const float*)d_in[3];
  const float* bk   = (const float*)d_in[4];
  const float* Wv   = (const float*)d_in[5];
  const float* bv   = (const float*)d_in[6];
  const float* Wo   = (const float*)d_in[7];
  const float* bo   = (const float*)d_in[8];
  const float* gamma = (const float*)d_in[9];
  const float* beta  = (const float*)d_in[10];
  float* out = (float*)d_out;

  unsigned short* hb   = (unsigned short*)d_ws;   // bf16 h; dead after gemm_qkv -> reused as ctx
  unsigned short* wqb  = hb  + 4194304;           // 4 weights contiguous (Wq|Wk|Wv|Wo)
  unsigned short* wkb  = wqb + 1048576;
  unsigned short* wvb  = wkb + 1048576;
  unsigned short* wob  = wvb + 1048576;
  unsigned short* qb   = wob + 1048576;           // bf16 [B,NH,T,D]
  unsigned short* kb   = qb  + 4194304;
  unsigned short* vtf  = kb  + 4194304;           // f16 [B,NH,D,T], written by gemm_qkv directly
  unsigned short* Opart = vtf + 4194304;          // bf16 partials (nparts x 8 MiB)
  unsigned short* ctxb = hb;                      // ctx aliases dead hb

  const size_t base = (size_t)(vtf + 4194304 - hb) * 2;  // bytes before Opart (40 MiB)
  int lsplit = 0;
  if (ws_size >= base + 2u * 8388608 + 2u * 262144) lsplit = 1;  // ~57 MiB
  const int nparts = 1 << lsplit;
  float* rsumP = (float*)(Opart + (size_t)nparts * 4194304);

  cast_all_k<<<8192, 256, 0, stream>>>(h, Wq, Wk, Wv, Wo, hb, wqb);
  gemm_qkv<<<dim3(16, 32), 256, 0, stream>>>(hb, wqb, bq, bk, bv, qb, kb, vtf);
  attn_k<<<dim3(TSEQ / 128, NH, BATCH << lsplit), 256, 0, stream>>>(
      qb, kb, vtf, ctxb, Opart, rsumP, lsplit, 32 >> lsplit);
  if (lsplit)
    combine_k<<<2048, 256, 0, stream>>>(Opart, rsumP, ctxb, nparts);
  gemm_out<<<dim3(16, 32), 256, 0, stream>>>(ctxb, wob, bo, h, out);
  ln_k<<<4096, 256, 0, stream>>>(out, gamma, beta);
}

// Round 7
// 204.315 us; speedup vs baseline: 1.1547x; 1.0256x over previous
//
#include <hip/hip_runtime.h>
#include <hip/hip_bf16.h>

#define NH   16
#define HD   64
#define HID  1024
#define TSEQ 2048
#define BATCH 2
#define KSCALE 0.18033688011112042f   // 0.125 * log2(e), folded into Wk/bk

typedef __attribute__((ext_vector_type(4))) float f32x4;
typedef __attribute__((ext_vector_type(8))) short s16x8;
typedef __attribute__((ext_vector_type(4))) short s16x4;
typedef __attribute__((ext_vector_type(8))) _Float16 f16x8;
typedef __attribute__((ext_vector_type(4))) _Float16 f16x4;
typedef __attribute__((ext_vector_type(2))) _Float16 f16x2;

__device__ __forceinline__ unsigned short f2bf(float f) {
  union { float f; unsigned int u; } v; v.f = f;
  unsigned int r = v.u + 0x7fffu + ((v.u >> 16) & 1u);
  return (unsigned short)(r >> 16);
}
__device__ __forceinline__ float bf2f(unsigned short b) {
  union { unsigned int u; float f; } v; v.u = ((unsigned int)b) << 16; return v.f;
}

// async global->LDS, 16B per lane; LDS dest must be wave-uniform base (+lane*16 by HW)
__device__ __forceinline__ void gll16(const void* g, void* l) {
  __builtin_amdgcn_global_load_lds(
      (const __attribute__((address_space(1))) unsigned int*)g,
      (__attribute__((address_space(3))) unsigned int*)l, 16, 0, 0);
}

// counted-vmcnt barrier: own-wave outstanding loads <= N, then collective barrier.
#define WAITBAR(N)                                                      \
  do {                                                                  \
    __builtin_amdgcn_sched_barrier(0);                                  \
    asm volatile("s_waitcnt vmcnt(" #N ")\n\ts_barrier" ::: "memory");  \
  } while (0)

// ---------------- one cast kernel: h + all 4 weights (Wk pre-scaled) ----------------
__global__ __launch_bounds__(256) void cast_all_k(
    const float* __restrict__ h,
    const float* __restrict__ w0, const float* __restrict__ w1,
    const float* __restrict__ w2, const float* __restrict__ w3,
    unsigned short* __restrict__ hb, unsigned short* __restrict__ wbase) {
  int i = blockIdx.x * 256 + threadIdx.x;  // 2097152 float4 total
  const float* src; unsigned short* dst; int idx; float sc = 1.f;
  if (i < 1048576) { src = h; dst = hb; idx = i; }
  else {
    int idx4 = i - 1048576;
    int w = idx4 >> 18;
    idx = idx4 & 262143;
    src = (w == 0) ? w0 : (w == 1) ? w1 : (w == 2) ? w2 : w3;
    dst = wbase + (size_t)(idx4 - idx) * 4;   // contiguous weight region
    if (w == 1) sc = KSCALE;
  }
  float4 v = ((const float4*)src)[idx];
  ushort4 o;
  o.x = f2bf(v.x * sc); o.y = f2bf(v.y * sc); o.z = f2bf(v.z * sc); o.w = f2bf(v.w * sc);
  ((ushort4*)dst)[idx] = o;
}

// ---------------- Fused QKV projection: one 4096x3072x1024 NT-GEMM ----------------
// 128x192 tile -> grid 512 = exactly 2 blocks/CU (no tail), ring-4 LDS (80 KB),
// prefetch distance 3, counted vmcnt (never 0 in main loop).
__global__ __launch_bounds__(256) void gemm_qkv(
    const unsigned short* __restrict__ hb,
    const unsigned short* __restrict__ wcat,   // [3072][1024] = Wq|Wk|Wv, Wk pre-scaled
    const float* __restrict__ bq, const float* __restrict__ bk, const float* __restrict__ bv,
    unsigned short* __restrict__ qo, unsigned short* __restrict__ ko,
    unsigned short* __restrict__ vto) {
  __shared__ unsigned short Ash[4][128 * 32];   // 4 x 8 KB
  __shared__ unsigned short Bsh[4][192 * 32];   // 4 x 12 KB  (total 80 KB -> 2 blocks/CU)
  const int tid = threadIdx.x, lane = tid & 63, wave = tid >> 6;
  const int l15 = lane & 15, quad = lane >> 4;
  const int wr = wave >> 1, wc = wave & 1;      // 2x2 waves, each 64x96 out
  const int bn = blockIdx.x * 192, bm = blockIdx.y * 128;
  const char* Ab = (const char*)(hb + (size_t)bm * HID);
  const char* Bb = (const char*)(wcat + (size_t)bn * HID);
  // staging: A tile [128 r][32 k] = 8 KB (2 issues), B tile [192 r][32 k] = 12 KB (3 issues)
  const int off = tid * 16;                 // byte offset within one 4 KB issue
  const int r0 = off >> 6, c0 = off & 63;   // 64 B per tile row
  const size_t ga0 = (size_t)r0 * (HID * 2) + c0;
  const size_t ga1 = ga0 + (size_t)64  * (HID * 2);
  const size_t gb2 = ga0 + (size_t)128 * (HID * 2);
  const int lb0 = wave * 512;               // LDS dest (elements); HW adds lane*16B
  const int lb1 = 2048 + wave * 512;
  const int lb2 = 4096 + wave * 512;

  f32x4 acc[4][6];
#pragma unroll
  for (int i = 0; i < 4; ++i)
#pragma unroll
    for (int j = 0; j < 6; ++j) acc[i][j] = f32x4{0.f, 0.f, 0.f, 0.f};

  auto stage = [&](int bufi, int k0) {      // 5 loads per thread per tile
    const size_t kb = (size_t)k0 * 2;
    gll16(Ab + ga0 + kb, &Ash[bufi][lb0]);
    gll16(Ab + ga1 + kb, &Ash[bufi][lb1]);
    gll16(Bb + ga0 + kb, &Bsh[bufi][lb0]);
    gll16(Bb + ga1 + kb, &Bsh[bufi][lb1]);
    gll16(Bb + gb2 + kb, &Bsh[bufi][lb2]);
  };
  auto compute = [&](int bufi) {
    s16x8 af[4], bfr[6];
#pragma unroll
    for (int i = 0; i < 4; ++i)
      af[i] = *(const s16x8*)(&Ash[bufi][(wr * 64 + i * 16 + l15) * 32 + quad * 8]);
#pragma unroll
    for (int j = 0; j < 6; ++j)
      bfr[j] = *(const s16x8*)(&Bsh[bufi][(wc * 96 + j * 16 + l15) * 32 + quad * 8]);
#pragma unroll
    for (int i = 0; i < 4; ++i)
#pragma unroll
      for (int j = 0; j < 6; ++j)
        acc[i][j] = __builtin_amdgcn_mfma_f32_16x16x32_bf16(af[i], bfr[j], acc[i][j], 0, 0, 0);
  };

  // prologue: tiles 0..2 in flight (15 outstanding/wave)
  stage(0, 0);
  stage(1, 32);
  stage(2, 64);
  int cur = 0, pf = 3;
  const int NT = HID / 32;                  // 32
  for (int t = 0; t < NT - 3; ++t) {        // t = 0..28
    WAITBAR(10);                            // tile t landed; t+1,t+2 stay in flight
    stage(pf, (t + 3) * 32);
    compute(cur);
    cur = (cur + 1) & 3;
    pf  = (pf + 1) & 3;
  }
  WAITBAR(10); compute(cur); cur = (cur + 1) & 3;   // t = NT-3
  WAITBAR(5);  compute(cur); cur = (cur + 1) & 3;   // t = NT-2
  WAITBAR(0);  compute(cur);                        // t = NT-1

  // epilogue: 16-col groups never straddle a 1024 boundary -> mat uniform per j
  const int rbase = bm + wr * 64;
#pragma unroll
  for (int j = 0; j < 6; ++j) {
    const int cg  = bn + wc * 96 + j * 16;  // group start (multiple of 16)
    const int mat = cg >> 10;               // 0=Q 1=K 2=V
    const int coln = (cg & 1023) + l15;     // column within matrix
    const int head = coln >> 6, d = coln & 63;
    if (mat == 2) {
      // V: f16, transposed [B,NH,D,T]; 4 consecutive t per lane = 8B store
      const float bb = bv[coln];
#pragma unroll
      for (int i = 0; i < 4; ++i) {
        const int row0 = rbase + i * 16 + quad * 4;
        const int bI = row0 >> 11, t0 = row0 & 2047;
        unsigned short o[4];
#pragma unroll
        for (int r = 0; r < 4; ++r) {
          _Float16 hv = (_Float16)(acc[i][j][r] + bb);
          o[r] = __builtin_bit_cast(unsigned short, hv);
        }
        *(s16x4*)(vto + ((size_t)((bI * NH + head) * HD + d)) * TSEQ + t0) = *(const s16x4*)o;
      }
    } else {
      unsigned short* dst = (mat == 0) ? qo : ko;
      const float bb = (mat == 0) ? bq[coln] : bk[coln] * KSCALE;
#pragma unroll
      for (int i = 0; i < 4; ++i) {
#pragma unroll
        for (int r = 0; r < 4; ++r) {
          const int row = rbase + i * 16 + quad * 4 + r;
          const int bI = row >> 11, t = row & 2047;
          dst[(((size_t)(bI * NH + head) * TSEQ) + t) * HD + d] = f2bf(acc[i][j][r] + bb);
        }
      }
    }
  }
}

// ---------------- Output projection: 128x64 tile, 5-ring depth-4 ----------------
__global__ __launch_bounds__(256) void gemm_out(
    const unsigned short* __restrict__ ctx, const unsigned short* __restrict__ wo,
    const float* __restrict__ bo, const float* __restrict__ hres,
    float* __restrict__ outf) {
  __shared__ unsigned short Ash[5][128 * 32];   // 5 x 8 KB
  __shared__ unsigned short Bsh[5][64 * 32];    // 5 x 4 KB  (total 60 KB)
  const int tid = threadIdx.x, lane = tid & 63, wave = tid >> 6;
  const int l15 = lane & 15, quad = lane >> 4;
  const int wr = wave >> 1, wc = wave & 1;      // each wave: 64 rows x 32 cols
  const int bn = blockIdx.x * 64, bm = blockIdx.y * 128;
  const char* Ab = (const char*)(ctx + (size_t)bm * HID);
  const char* Bb = (const char*)(wo + (size_t)bn * HID);
  const int off = tid * 16;
  const int r0 = off >> 6, c0 = off & 63;
  const size_t ga0 = (size_t)r0 * (HID * 2) + c0;
  const size_t ga1 = ga0 + (size_t)64 * (HID * 2);
  const int lb0 = wave * 512, lb1 = 2048 + wave * 512;

  f32x4 acc[4][2];
#pragma unroll
  for (int i = 0; i < 4; ++i)
#pragma unroll
    for (int j = 0; j < 2; ++j) acc[i][j] = f32x4{0.f, 0.f, 0.f, 0.f};

  auto stage = [&](int bufi, int k0) {
    const size_t kb = (size_t)k0 * 2;
    gll16(Ab + ga0 + kb, &Ash[bufi][lb0]);
    gll16(Ab + ga1 + kb, &Ash[bufi][lb1]);
    gll16(Bb + ga0 + kb, &Bsh[bufi][lb0]);   // 64x32 B-tile = exactly one issue
  };
  auto compute = [&](int bufi) {
    s16x8 af[4], bfr[2];
#pragma unroll
    for (int i = 0; i < 4; ++i)
      af[i] = *(const s16x8*)(&Ash[bufi][(wr * 64 + i * 16 + l15) * 32 + quad * 8]);
#pragma unroll
    for (int j = 0; j < 2; ++j)
      bfr[j] = *(const s16x8*)(&Bsh[bufi][(wc * 32 + j * 16 + l15) * 32 + quad * 8]);
#pragma unroll
    for (int i = 0; i < 4; ++i)
#pragma unroll
      for (int j = 0; j < 2; ++j)
        acc[i][j] = __builtin_amdgcn_mfma_f32_16x16x32_bf16(af[i], bfr[j], acc[i][j], 0, 0, 0);
  };

  stage(0, 0);
  stage(1, 32);
  stage(2, 64);
  stage(3, 96);
  int cur = 0, pf = 4;
  const int NT = HID / 32;
  for (int t = 0; t < NT - 4; ++t) {
    WAITBAR(9);                             // 3 loads/tile: tile t home, 3 tiles in flight
    stage(pf, (t + 4) * 32);
    compute(cur);
    cur = (cur == 4) ? 0 : cur + 1;
    pf  = (pf  == 4) ? 0 : pf + 1;
  }
  WAITBAR(9); compute(cur); cur = (cur == 4) ? 0 : cur + 1;    // t = NT-4
  WAITBAR(6); compute(cur); cur = (cur == 4) ? 0 : cur + 1;    // t = NT-3
  WAITBAR(3); compute(cur); cur = (cur == 4) ? 0 : cur + 1;    // t = NT-2
  WAITBAR(0); compute(cur);                                    // t = NT-1

#pragma unroll
  for (int j = 0; j < 2; ++j) {
    const int col = bn + wc * 32 + j * 16 + l15;
    const float bb = bo[col];
#pragma unroll
    for (int i = 0; i < 4; ++i) {
#pragma unroll
      for (int r = 0; r < 4; ++r) {
        const int row = bm + wr * 64 + i * 16 + quad * 4 + r;
        const size_t o = (size_t)row * HID + col;
        outf[o] = acc[i][j][r] + bb + hres[o];
      }
    }
  }
}

// ---------------- Flash attention: S^T form, K=32 PV, 3-buffer 1-barrier pipeline ----------------
// Per iter: stage(t+1) -> barrier -> prefetch regs(t+2) -> QK^T(t+1) -> PV(t) || exp(t+1).
// PV(t) (MFMA, depends on exp(t)) overlaps exp(t+1) (VALU) - independent chains.
// rsum via ones-row MFMA into accR (f32 accum): no VALU adds, no cross-lane reduce.
__global__ __launch_bounds__(256, 2) void attn_k(
    const unsigned short* __restrict__ qb, const unsigned short* __restrict__ kb,
    const unsigned short* __restrict__ vt, unsigned short* __restrict__ ctx,
    unsigned short* __restrict__ Opart, float* __restrict__ rsumP,
    int lsplit, int ntiles) {
  __shared__ unsigned short Ksh[3][64 * 72];   // bf16 [key][d], 3-ring
  __shared__ unsigned short Vsh[3][64 * 72];   // f16  [d][key-permuted], 3-ring

  const int tid = threadIdx.x, lane = tid & 63, wave = tid >> 6;
  const int l15 = lane & 15, quad = lane >> 4;
  const int z = blockIdx.z;
  const int b = z >> lsplit;
  const int part = z & ((1 << lsplit) - 1);
  const int h = blockIdx.y, qt = blockIdx.x;
  const size_t ho = ((size_t)(b * NH + h)) * TSEQ * HD;
  const unsigned short* Qh = qb + ho;
  const unsigned short* Kh = kb + ho;
  const unsigned short* Vh = vt + ho;
  const int q0 = qt * 128 + wave * 32;
  const int kt0 = part * ntiles;

  s16x8 qf[2][2];
#pragma unroll
  for (int s = 0; s < 2; ++s)
#pragma unroll
    for (int ks = 0; ks < 2; ++ks)
      qf[s][ks] = *(const s16x8*)(Qh + (size_t)(q0 + s * 16 + l15) * HD + ks * 32 + quad * 8);

  f32x4 accO[4][2];   // O^T: [d-strip n2][q-col s], lane=(d=quad*4+r, q=l15)
  f32x4 accR[2];      // ones-row PV: every lane ends with full key-sum for q=l15
#pragma unroll
  for (int n2 = 0; n2 < 4; ++n2)
#pragma unroll
    for (int s = 0; s < 2; ++s) accO[n2][s] = f32x4{0.f, 0.f, 0.f, 0.f};
  accR[0] = accR[1] = f32x4{0.f, 0.f, 0.f, 0.f};
  const f16x8 vones = {(_Float16)1.f, (_Float16)1.f, (_Float16)1.f, (_Float16)1.f,
                       (_Float16)1.f, (_Float16)1.f, (_Float16)1.f, (_Float16)1.f};

  const int sr = tid >> 3, sc = (tid & 7) * 8;
  // V permuted write base: c = key-chunk index 0..7, keys 8c..8c+7 ->
  // two 4-key runs at vwb and vwb+8 (verified element-wise, R6-passing)
  const int c = tid & 7;
  const int vwb = (c >> 2) * 32 + (c & 1) * 16 + ((c & 3) >> 1) * 4;
  s16x8 kreg[2], vreg[2];

  auto ldregs = [&](int kt) {
    const int k0n = (kt0 + kt) * 64;
#pragma unroll
    for (int hf = 0; hf < 2; ++hf) {
      kreg[hf] = *(const s16x8*)(Kh + (size_t)(k0n + sr + hf * 32) * HD + sc);
      vreg[hf] = *(const s16x8*)(Vh + (size_t)(sr + hf * 32) * TSEQ + k0n + sc);
    }
  };
  auto wlds = [&](int bi) {
#pragma unroll
    for (int hf = 0; hf < 2; ++hf) {
      *(s16x8*)(Ksh[bi] + (sr + hf * 32) * 72 + sc) = kreg[hf];
      const s16x4* vh = (const s16x4*)&vreg[hf];
      *(s16x4*)(Vsh[bi] + (sr + hf * 32) * 72 + vwb)     = vh[0];
      *(s16x4*)(Vsh[bi] + (sr + hf * 32) * 72 + vwb + 8) = vh[1];
    }
  };

  f32x4 accS[2][4];
  f16x4 pP[2][4];

  auto qkt = [&](int bi) {
#pragma unroll
    for (int s = 0; s < 2; ++s)
#pragma unroll
      for (int n = 0; n < 4; ++n) accS[s][n] = f32x4{0.f, 0.f, 0.f, 0.f};
#pragma unroll
    for (int ks = 0; ks < 2; ++ks) {
#pragma unroll
      for (int n = 0; n < 4; ++n) {
        s16x8 kf = *(const s16x8*)(Ksh[bi] + (n * 16 + l15) * 72 + ks * 32 + quad * 8);
#pragma unroll
        for (int s = 0; s < 2; ++s)
          accS[s][n] = __builtin_amdgcn_mfma_f32_16x16x32_bf16(kf, qf[s][ks], accS[s][n], 0, 0, 0);
      }
    }
  };
  auto expp = [&]() {   // accS -> pP (f16 pairs); no rsum adds (MFMA handles it)
#pragma unroll
    for (int s = 0; s < 2; ++s)
#pragma unroll
      for (int n = 0; n < 4; ++n) {
        float e0 = __builtin_amdgcn_exp2f(accS[s][n][0]);
        float e1 = __builtin_amdgcn_exp2f(accS[s][n][1]);
        float e2 = __builtin_amdgcn_exp2f(accS[s][n][2]);
        float e3 = __builtin_amdgcn_exp2f(accS[s][n][3]);
        f16x2 lo = __builtin_bit_cast(f16x2, __builtin_amdgcn_cvt_pkrtz(e0, e1));
        f16x2 hi = __builtin_bit_cast(f16x2, __builtin_amdgcn_cvt_pkrtz(e2, e3));
        pP[s][n] = f16x4{lo[0], lo[1], hi[0], hi[1]};
      }
  };
  auto pv = [&](int bi) {   // K=32 full-rate f16 MFMA + ones-row rsum
#pragma unroll
    for (int kk = 0; kk < 2; ++kk) {
      union { f16x4 h[2]; f16x8 v8; } u0, u1;
      u0.h[0] = pP[0][2 * kk]; u0.h[1] = pP[0][2 * kk + 1];
      u1.h[0] = pP[1][2 * kk]; u1.h[1] = pP[1][2 * kk + 1];
      accR[0] = __builtin_amdgcn_mfma_f32_16x16x32_f16(vones, u0.v8, accR[0], 0, 0, 0);
      accR[1] = __builtin_amdgcn_mfma_f32_16x16x32_f16(vones, u1.v8, accR[1], 0, 0, 0);
#pragma unroll
      for (int n2 = 0; n2 < 4; ++n2) {
        f16x8 vA = *(const f16x8*)(Vsh[bi] + (n2 * 16 + l15) * 72 + kk * 32 + quad * 8);
        accO[n2][0] = __builtin_amdgcn_mfma_f32_16x16x32_f16(vA, u0.v8, accO[n2][0], 0, 0, 0);
        accO[n2][1] = __builtin_amdgcn_mfma_f32_16x16x32_f16(vA, u1.v8, accO[n2][1], 0, 0, 0);
      }
    }
  };

  // prologue
  ldregs(0);
  wlds(0);
  __syncthreads();
  if (ntiles > 1) ldregs(1);
  qkt(0);
  expp();

  int b0 = 0, b1 = 1;
  for (int t = 0; t < ntiles - 1; ++t) {
    wlds(b1);                     // stage tile t+1 (regs loaded at iter t-1)
    __syncthreads();              // writes visible; 3-ring guards reuse
    if (t + 2 < ntiles) ldregs(t + 2);
    qkt(b1);                      // accS(t+1)  [MFMA]
    pv(b0);                       // PV(t) w/ pP [MFMA]  - independent of accS
    expp();                       // exp(t+1) -> pP [VALU] - overlaps PV issue
    b0 = b1; b1 = (b1 == 2) ? 0 : b1 + 1;
  }
  pv(b0);                         // PV(ntiles-1)

  float rsum[2] = {accR[0][0], accR[1][0]};   // all lanes hold their q's full sum

  if (lsplit) {
    const int slot = (part * BATCH + b) * NH + h;
    const size_t ob = (size_t)slot * TSEQ * HD;
#pragma unroll
    for (int s = 0; s < 2; ++s) {
      const int t = q0 + s * 16 + l15;
#pragma unroll
      for (int n2 = 0; n2 < 4; ++n2) {
        const int d0 = n2 * 16 + quad * 4;
        unsigned short o[4];
#pragma unroll
        for (int r = 0; r < 4; ++r) o[r] = f2bf(accO[n2][s][r]);
        *(s16x4*)(Opart + ob + (size_t)t * HD + d0) = *(const s16x4*)o;
      }
    }
    if (quad == 0) {
      const size_t rb = (size_t)slot * TSEQ;
#pragma unroll
      for (int s = 0; s < 2; ++s)
        rsumP[rb + q0 + s * 16 + l15] = rsum[s];
    }
  } else {
#pragma unroll
    for (int s = 0; s < 2; ++s) {
      const int t = q0 + s * 16 + l15;
      const float inv = 1.f / rsum[s];
#pragma unroll
      for (int n2 = 0; n2 < 4; ++n2) {
        const int d0 = n2 * 16 + quad * 4;
        unsigned short o[4];
#pragma unroll
        for (int r = 0; r < 4; ++r) o[r] = f2bf(accO[n2][s][r] * inv);
        *(s16x4*)(ctx + ((size_t)(b * TSEQ + t)) * HID + h * HD + d0) = *(const s16x4*)o;
      }
    }
  }
}

// ---------------- combine K-split parts: ctx = sum(O_p)/sum(r_p), bf16 ----------------
__global__ __launch_bounds__(256) void combine_k(
    const unsigned short* __restrict__ Opart, const float* __restrict__ rsumP,
    unsigned short* __restrict__ ctx, int nparts) {
  const int gtid = blockIdx.x * 256 + threadIdx.x;  // 524288 total
  const int d = (gtid & 7) * 8;
  const int rem = gtid >> 3;
  const int t = rem & 2047;
  const int bh = rem >> 11;          // b*NH + h  (0..31)
  float acc[8] = {0, 0, 0, 0, 0, 0, 0, 0};
  float rs = 0.f;
  for (int p = 0; p < nparts; ++p) {
    const int slot = p * 32 + bh;
    s16x8 a = *(const s16x8*)(Opart + ((size_t)slot * TSEQ + t) * HD + d);
#pragma unroll
    for (int j = 0; j < 8; ++j) acc[j] += bf2f(((const unsigned short*)&a)[j]);
    rs += rsumP[(size_t)slot * TSEQ + t];
  }
  const float inv = 1.f / rs;
  unsigned short o[8];
#pragma unroll
  for (int j = 0; j < 8; ++j) o[j] = f2bf(acc[j] * inv);
  const int b = bh >> 4, h = bh & 15;
  *(s16x8*)(ctx + ((size_t)(b * TSEQ + t)) * HID + h * HD + d) = *(const s16x8*)o;
}

// ---------------- In-place LayerNorm over rows of 1024 ----------------
__global__ __launch_bounds__(256) void ln_k(float* __restrict__ io,
                                            const float* __restrict__ gamma,
                                            const float* __restrict__ beta) {
  const int row = blockIdx.x, tid = threadIdx.x;
  float x[4]; float s = 0.f, s2 = 0.f;
#pragma unroll
  for (int i = 0; i < 4; ++i) {
    x[i] = io[(size_t)row * HID + tid + i * 256];
    s += x[i]; s2 += x[i] * x[i];
  }
#pragma unroll
  for (int off = 1; off < 64; off <<= 1) {
    s  += __shfl_xor(s, off, 64);
    s2 += __shfl_xor(s2, off, 64);
  }
  __shared__ float red[8];
  const int wave = tid >> 6;
  if ((tid & 63) == 0) { red[wave] = s; red[wave + 4] = s2; }
  __syncthreads();
  s  = red[0] + red[1] + red[2] + red[3];
  s2 = red[4] + red[5] + red[6] + red[7];
  const float mean = s * (1.f / HID);
  const float var  = s2 * (1.f / HID) - mean * mean;
  const float rstd = rsqrtf(var + 1e-6f);
#pragma unroll
  for (int i = 0; i < 4; ++i) {
    const int col = tid + i * 256;
    io[(size_t)row * HID + col] = (x[i] - mean) * rstd * gamma[col] + beta[col];
  }
}

extern "C" void kernel_launch(void* const* d_in, const int* in_sizes, int n_in,
                              void* d_out, int out_size, void* d_ws, size_t ws_size,
                              hipStream_t stream) {
  const float* h    = (const float*)d_in[0];
  const float* Wq   = (const float*)d_in[1];
  const float* bq   = (const float*)d_in[2];
  const float* Wk   = (const float*)d_in[3];
  const float* bk   = (const float*)d_in[4];
  const float* Wv   = (const float*)d_in[5];
  const float* bv   = (const float*)d_in[6];
  const float* Wo   = (const float*)d_in[7];
  const float* bo   = (const float*)d_in[8];
  const float* gamma = (const float*)d_in[9];
  const float* beta  = (const float*)d_in[10];
  float* out = (float*)d_out;

  unsigned short* hb   = (unsigned short*)d_ws;   // bf16 h; dead after gemm_qkv -> reused as ctx
  unsigned short* wqb  = hb  + 4194304;           // 4 weights contiguous (Wq|Wk|Wv|Wo)
  unsigned short* wkb  = wqb + 1048576;
  unsigned short* wvb  = wkb + 1048576;
  unsigned short* wob  = wvb + 1048576;
  unsigned short* qb   = wob + 1048576;           // bf16 [B,NH,T,D]
  unsigned short* kb   = qb  + 4194304;
  unsigned short* vtf  = kb  + 4194304;           // f16 [B,NH,D,T], written by gemm_qkv directly
  unsigned short* Opart = vtf + 4194304;          // bf16 partials (nparts x 8 MiB)
  unsigned short* ctxb = hb;                      // ctx aliases dead hb

  const size_t base = (size_t)(vtf + 4194304 - hb) * 2;  // bytes before Opart (40 MiB)
  int lsplit = 0;
  if (ws_size >= base + 2u * 8388608 + 2u * 262144) lsplit = 1;  // ~57 MiB
  const int nparts = 1 << lsplit;
  float* rsumP = (float*)(Opart + (size_t)nparts * 4194304);

  cast_all_k<<<8192, 256, 0, stream>>>(h, Wq, Wk, Wv, Wo, hb, wqb);
  gemm_qkv<<<dim3(16, 32), 256, 0, stream>>>(hb, wqb, bq, bk, bv, qb, kb, vtf);
  attn_k<<<dim3(TSEQ / 128, NH, BATCH << lsplit), 256, 0, stream>>>(
      qb, kb, vtf, ctxb, Opart, rsumP, lsplit, 32 >> lsplit);
  if (lsplit)
    combine_k<<<2048, 256, 0, stream>>>(Opart, rsumP, ctxb, nparts);
  gemm_out<<<dim3(16, 32), 256, 0, stream>>>(ctxb, wob, bo, h, out);
  ln_k<<<4096, 256, 0, stream>>>(out, gamma, beta);
}

// Round 8
// 198.397 us; speedup vs baseline: 1.1892x; 1.0298x over previous
//
#include <hip/hip_runtime.h>
#include <hip/hip_bf16.h>

#define NH   16
#define HD   64
#define HID  1024
#define TSEQ 2048
#define BATCH 2
#define KSCALE 0.18033688011112042f   // 0.125 * log2(e), folded into Wk/bk

typedef __attribute__((ext_vector_type(4))) float f32x4;
typedef __attribute__((ext_vector_type(8))) short s16x8;
typedef __attribute__((ext_vector_type(4))) short s16x4;
typedef __attribute__((ext_vector_type(8))) _Float16 f16x8;
typedef __attribute__((ext_vector_type(4))) _Float16 f16x4;
typedef __attribute__((ext_vector_type(2))) _Float16 f16x2;

__device__ __forceinline__ unsigned short f2bf(float f) {
  union { float f; unsigned int u; } v; v.f = f;
  unsigned int r = v.u + 0x7fffu + ((v.u >> 16) & 1u);
  return (unsigned short)(r >> 16);
}
__device__ __forceinline__ float bf2f(unsigned short b) {
  union { unsigned int u; float f; } v; v.u = ((unsigned int)b) << 16; return v.f;
}

// async global->LDS, 16B per lane; LDS dest must be wave-uniform base (+lane*16 by HW)
__device__ __forceinline__ void gll16(const void* g, void* l) {
  __builtin_amdgcn_global_load_lds(
      (const __attribute__((address_space(1))) unsigned int*)g,
      (__attribute__((address_space(3))) unsigned int*)l, 16, 0, 0);
}

// counted-vmcnt barrier: own-wave outstanding loads <= N, then collective barrier.
#define WAITBAR(N)                                                      \
  do {                                                                  \
    __builtin_amdgcn_sched_barrier(0);                                  \
    asm volatile("s_waitcnt vmcnt(" #N ")\n\ts_barrier" ::: "memory");  \
  } while (0)

// ---------------- one cast kernel: h + all 4 weights (Wk pre-scaled) ----------------
__global__ __launch_bounds__(256) void cast_all_k(
    const float* __restrict__ h,
    const float* __restrict__ w0, const float* __restrict__ w1,
    const float* __restrict__ w2, const float* __restrict__ w3,
    unsigned short* __restrict__ hb, unsigned short* __restrict__ wbase) {
  int i = blockIdx.x * 256 + threadIdx.x;  // 2097152 float4 total
  const float* src; unsigned short* dst; int idx; float sc = 1.f;
  if (i < 1048576) { src = h; dst = hb; idx = i; }
  else {
    int idx4 = i - 1048576;
    int w = idx4 >> 18;
    idx = idx4 & 262143;
    src = (w == 0) ? w0 : (w == 1) ? w1 : (w == 2) ? w2 : w3;
    dst = wbase + (size_t)(idx4 - idx) * 4;   // contiguous weight region
    if (w == 1) sc = KSCALE;
  }
  float4 v = ((const float4*)src)[idx];
  ushort4 o;
  o.x = f2bf(v.x * sc); o.y = f2bf(v.y * sc); o.z = f2bf(v.z * sc); o.w = f2bf(v.w * sc);
  ((ushort4*)dst)[idx] = o;
}

// ---------------- Fused QKV projection: one 4096x3072x1024 NT-GEMM ----------------
// 128x192 tile -> grid 512 = exactly 2 blocks/CU (no tail), ring-4 LDS (80 KB),
// prefetch distance 3, counted vmcnt (never 0 in main loop).
__global__ __launch_bounds__(256) void gemm_qkv(
    const unsigned short* __restrict__ hb,
    const unsigned short* __restrict__ wcat,   // [3072][1024] = Wq|Wk|Wv, Wk pre-scaled
    const float* __restrict__ bq, const float* __restrict__ bk, const float* __restrict__ bv,
    unsigned short* __restrict__ qo, unsigned short* __restrict__ ko,
    unsigned short* __restrict__ vto) {
  __shared__ unsigned short Ash[4][128 * 32];   // 4 x 8 KB
  __shared__ unsigned short Bsh[4][192 * 32];   // 4 x 12 KB  (total 80 KB -> 2 blocks/CU)
  const int tid = threadIdx.x, lane = tid & 63, wave = tid >> 6;
  const int l15 = lane & 15, quad = lane >> 4;
  const int wr = wave >> 1, wc = wave & 1;      // 2x2 waves, each 64x96 out
  const int bn = blockIdx.x * 192, bm = blockIdx.y * 128;
  const char* Ab = (const char*)(hb + (size_t)bm * HID);
  const char* Bb = (const char*)(wcat + (size_t)bn * HID);
  // staging: A tile [128 r][32 k] = 8 KB (2 issues), B tile [192 r][32 k] = 12 KB (3 issues)
  const int off = tid * 16;                 // byte offset within one 4 KB issue
  const int r0 = off >> 6, c0 = off & 63;   // 64 B per tile row
  const size_t ga0 = (size_t)r0 * (HID * 2) + c0;
  const size_t ga1 = ga0 + (size_t)64  * (HID * 2);
  const size_t gb2 = ga0 + (size_t)128 * (HID * 2);
  const int lb0 = wave * 512;               // LDS dest (elements); HW adds lane*16B
  const int lb1 = 2048 + wave * 512;
  const int lb2 = 4096 + wave * 512;

  f32x4 acc[4][6];
#pragma unroll
  for (int i = 0; i < 4; ++i)
#pragma unroll
    for (int j = 0; j < 6; ++j) acc[i][j] = f32x4{0.f, 0.f, 0.f, 0.f};

  auto stage = [&](int bufi, int k0) {      // 5 loads per thread per tile
    const size_t kb = (size_t)k0 * 2;
    gll16(Ab + ga0 + kb, &Ash[bufi][lb0]);
    gll16(Ab + ga1 + kb, &Ash[bufi][lb1]);
    gll16(Bb + ga0 + kb, &Bsh[bufi][lb0]);
    gll16(Bb + ga1 + kb, &Bsh[bufi][lb1]);
    gll16(Bb + gb2 + kb, &Bsh[bufi][lb2]);
  };
  auto compute = [&](int bufi) {
    s16x8 af[4], bfr[6];
#pragma unroll
    for (int i = 0; i < 4; ++i)
      af[i] = *(const s16x8*)(&Ash[bufi][(wr * 64 + i * 16 + l15) * 32 + quad * 8]);
#pragma unroll
    for (int j = 0; j < 6; ++j)
      bfr[j] = *(const s16x8*)(&Bsh[bufi][(wc * 96 + j * 16 + l15) * 32 + quad * 8]);
#pragma unroll
    for (int i = 0; i < 4; ++i)
#pragma unroll
      for (int j = 0; j < 6; ++j)
        acc[i][j] = __builtin_amdgcn_mfma_f32_16x16x32_bf16(af[i], bfr[j], acc[i][j], 0, 0, 0);
  };

  // prologue: tiles 0..2 in flight (15 outstanding/wave)
  stage(0, 0);
  stage(1, 32);
  stage(2, 64);
  int cur = 0, pf = 3;
  const int NT = HID / 32;                  // 32
  for (int t = 0; t < NT - 3; ++t) {        // t = 0..28
    WAITBAR(10);                            // tile t landed; t+1,t+2 stay in flight
    stage(pf, (t + 3) * 32);
    compute(cur);
    cur = (cur + 1) & 3;
    pf  = (pf + 1) & 3;
  }
  WAITBAR(10); compute(cur); cur = (cur + 1) & 3;   // t = NT-3
  WAITBAR(5);  compute(cur); cur = (cur + 1) & 3;   // t = NT-2
  WAITBAR(0);  compute(cur);                        // t = NT-1

  // epilogue: 16-col groups never straddle a 1024 boundary -> mat uniform per j
  const int rbase = bm + wr * 64;
#pragma unroll
  for (int j = 0; j < 6; ++j) {
    const int cg  = bn + wc * 96 + j * 16;  // group start (multiple of 16)
    const int mat = cg >> 10;               // 0=Q 1=K 2=V
    const int coln = (cg & 1023) + l15;     // column within matrix
    const int head = coln >> 6, d = coln & 63;
    if (mat == 2) {
      // V: f16, transposed [B,NH,D,T]; 4 consecutive t per lane = 8B store
      const float bb = bv[coln];
#pragma unroll
      for (int i = 0; i < 4; ++i) {
        const int row0 = rbase + i * 16 + quad * 4;
        const int bI = row0 >> 11, t0 = row0 & 2047;
        unsigned short o[4];
#pragma unroll
        for (int r = 0; r < 4; ++r) {
          _Float16 hv = (_Float16)(acc[i][j][r] + bb);
          o[r] = __builtin_bit_cast(unsigned short, hv);
        }
        *(s16x4*)(vto + ((size_t)((bI * NH + head) * HD + d)) * TSEQ + t0) = *(const s16x4*)o;
      }
    } else {
      unsigned short* dst = (mat == 0) ? qo : ko;
      const float bb = (mat == 0) ? bq[coln] : bk[coln] * KSCALE;
#pragma unroll
      for (int i = 0; i < 4; ++i) {
#pragma unroll
        for (int r = 0; r < 4; ++r) {
          const int row = rbase + i * 16 + quad * 4 + r;
          const int bI = row >> 11, t = row & 2047;
          dst[(((size_t)(bI * NH + head) * TSEQ) + t) * HD + d] = f2bf(acc[i][j][r] + bb);
        }
      }
    }
  }
}

// ---------------- Output projection: 128x64 tile, 5-ring depth-4 ----------------
__global__ __launch_bounds__(256) void gemm_out(
    const unsigned short* __restrict__ ctx, const unsigned short* __restrict__ wo,
    const float* __restrict__ bo, const float* __restrict__ hres,
    float* __restrict__ outf) {
  __shared__ unsigned short Ash[5][128 * 32];   // 5 x 8 KB
  __shared__ unsigned short Bsh[5][64 * 32];    // 5 x 4 KB  (total 60 KB)
  const int tid = threadIdx.x, lane = tid & 63, wave = tid >> 6;
  const int l15 = lane & 15, quad = lane >> 4;
  const int wr = wave >> 1, wc = wave & 1;      // each wave: 64 rows x 32 cols
  const int bn = blockIdx.x * 64, bm = blockIdx.y * 128;
  const char* Ab = (const char*)(ctx + (size_t)bm * HID);
  const char* Bb = (const char*)(wo + (size_t)bn * HID);
  const int off = tid * 16;
  const int r0 = off >> 6, c0 = off & 63;
  const size_t ga0 = (size_t)r0 * (HID * 2) + c0;
  const size_t ga1 = ga0 + (size_t)64 * (HID * 2);
  const int lb0 = wave * 512, lb1 = 2048 + wave * 512;

  f32x4 acc[4][2];
#pragma unroll
  for (int i = 0; i < 4; ++i)
#pragma unroll
    for (int j = 0; j < 2; ++j) acc[i][j] = f32x4{0.f, 0.f, 0.f, 0.f};

  auto stage = [&](int bufi, int k0) {
    const size_t kb = (size_t)k0 * 2;
    gll16(Ab + ga0 + kb, &Ash[bufi][lb0]);
    gll16(Ab + ga1 + kb, &Ash[bufi][lb1]);
    gll16(Bb + ga0 + kb, &Bsh[bufi][lb0]);   // 64x32 B-tile = exactly one issue
  };
  auto compute = [&](int bufi) {
    s16x8 af[4], bfr[2];
#pragma unroll
    for (int i = 0; i < 4; ++i)
      af[i] = *(const s16x8*)(&Ash[bufi][(wr * 64 + i * 16 + l15) * 32 + quad * 8]);
#pragma unroll
    for (int j = 0; j < 2; ++j)
      bfr[j] = *(const s16x8*)(&Bsh[bufi][(wc * 32 + j * 16 + l15) * 32 + quad * 8]);
#pragma unroll
    for (int i = 0; i < 4; ++i)
#pragma unroll
      for (int j = 0; j < 2; ++j)
        acc[i][j] = __builtin_amdgcn_mfma_f32_16x16x32_bf16(af[i], bfr[j], acc[i][j], 0, 0, 0);
  };

  stage(0, 0);
  stage(1, 32);
  stage(2, 64);
  stage(3, 96);
  int cur = 0, pf = 4;
  const int NT = HID / 32;
  for (int t = 0; t < NT - 4; ++t) {
    WAITBAR(9);                             // 3 loads/tile: tile t home, 3 tiles in flight
    stage(pf, (t + 4) * 32);
    compute(cur);
    cur = (cur == 4) ? 0 : cur + 1;
    pf  = (pf  == 4) ? 0 : pf + 1;
  }
  WAITBAR(9); compute(cur); cur = (cur == 4) ? 0 : cur + 1;    // t = NT-4
  WAITBAR(6); compute(cur); cur = (cur == 4) ? 0 : cur + 1;    // t = NT-3
  WAITBAR(3); compute(cur); cur = (cur == 4) ? 0 : cur + 1;    // t = NT-2
  WAITBAR(0); compute(cur);                                    // t = NT-1

#pragma unroll
  for (int j = 0; j < 2; ++j) {
    const int col = bn + wc * 32 + j * 16 + l15;
    const float bb = bo[col];
#pragma unroll
    for (int i = 0; i < 4; ++i) {
#pragma unroll
      for (int r = 0; r < 4; ++r) {
        const int row = bm + wr * 64 + i * 16 + quad * 4 + r;
        const size_t o = (size_t)row * HID + col;
        outf[o] = acc[i][j][r] + bb + hres[o];
      }
    }
  }
}

// ---------------- Flash attention: S^T form, K=32 PV, 3-buffer 1-barrier pipeline ----------------
// lsplit=0: 512 blocks = exactly 2/CU, full K walk, O accumulated in f32, no combine pass.
// Per iter: stage(t+1) -> barrier -> prefetch regs(t+2) -> QK^T(t+1) -> PV(t) || exp(t+1).
// rsum via ones-row MFMA into accR. s_setprio(1) around MFMA clusters (T5).
__global__ __launch_bounds__(256, 2) void attn_k(
    const unsigned short* __restrict__ qb, const unsigned short* __restrict__ kb,
    const unsigned short* __restrict__ vt, unsigned short* __restrict__ ctx,
    unsigned short* __restrict__ Opart, float* __restrict__ rsumP,
    int lsplit, int ntiles) {
  __shared__ unsigned short Ksh[3][64 * 72];   // bf16 [key][d], 3-ring
  __shared__ unsigned short Vsh[3][64 * 72];   // f16  [d][key-permuted], 3-ring

  const int tid = threadIdx.x, lane = tid & 63, wave = tid >> 6;
  const int l15 = lane & 15, quad = lane >> 4;
  const int z = blockIdx.z;
  const int b = z >> lsplit;
  const int part = z & ((1 << lsplit) - 1);
  const int h = blockIdx.y, qt = blockIdx.x;
  const size_t ho = ((size_t)(b * NH + h)) * TSEQ * HD;
  const unsigned short* Qh = qb + ho;
  const unsigned short* Kh = kb + ho;
  const unsigned short* Vh = vt + ho;
  const int q0 = qt * 128 + wave * 32;
  const int kt0 = part * ntiles;

  s16x8 qf[2][2];
#pragma unroll
  for (int s = 0; s < 2; ++s)
#pragma unroll
    for (int ks = 0; ks < 2; ++ks)
      qf[s][ks] = *(const s16x8*)(Qh + (size_t)(q0 + s * 16 + l15) * HD + ks * 32 + quad * 8);

  f32x4 accO[4][2];   // O^T: [d-strip n2][q-col s], lane=(d=quad*4+r, q=l15)
  f32x4 accR[2];      // ones-row PV: every lane ends with full key-sum for q=l15
#pragma unroll
  for (int n2 = 0; n2 < 4; ++n2)
#pragma unroll
    for (int s = 0; s < 2; ++s) accO[n2][s] = f32x4{0.f, 0.f, 0.f, 0.f};
  accR[0] = accR[1] = f32x4{0.f, 0.f, 0.f, 0.f};
  const f16x8 vones = {(_Float16)1.f, (_Float16)1.f, (_Float16)1.f, (_Float16)1.f,
                       (_Float16)1.f, (_Float16)1.f, (_Float16)1.f, (_Float16)1.f};

  const int sr = tid >> 3, sc = (tid & 7) * 8;
  // V permuted write base: c = key-chunk index 0..7, keys 8c..8c+7 ->
  // two 4-key runs at vwb and vwb+8 (verified element-wise, R6-passing)
  const int c = tid & 7;
  const int vwb = (c >> 2) * 32 + (c & 1) * 16 + ((c & 3) >> 1) * 4;
  s16x8 kreg[2], vreg[2];

  auto ldregs = [&](int kt) {
    const int k0n = (kt0 + kt) * 64;
#pragma unroll
    for (int hf = 0; hf < 2; ++hf) {
      kreg[hf] = *(const s16x8*)(Kh + (size_t)(k0n + sr + hf * 32) * HD + sc);
      vreg[hf] = *(const s16x8*)(Vh + (size_t)(sr + hf * 32) * TSEQ + k0n + sc);
    }
  };
  auto wlds = [&](int bi) {
#pragma unroll
    for (int hf = 0; hf < 2; ++hf) {
      *(s16x8*)(Ksh[bi] + (sr + hf * 32) * 72 + sc) = kreg[hf];
      const s16x4* vh = (const s16x4*)&vreg[hf];
      *(s16x4*)(Vsh[bi] + (sr + hf * 32) * 72 + vwb)     = vh[0];
      *(s16x4*)(Vsh[bi] + (sr + hf * 32) * 72 + vwb + 8) = vh[1];
    }
  };

  f32x4 accS[2][4];
  f16x4 pP[2][4];

  auto qkt = [&](int bi) {
#pragma unroll
    for (int s = 0; s < 2; ++s)
#pragma unroll
      for (int n = 0; n < 4; ++n) accS[s][n] = f32x4{0.f, 0.f, 0.f, 0.f};
    __builtin_amdgcn_s_setprio(1);
#pragma unroll
    for (int ks = 0; ks < 2; ++ks) {
#pragma unroll
      for (int n = 0; n < 4; ++n) {
        s16x8 kf = *(const s16x8*)(Ksh[bi] + (n * 16 + l15) * 72 + ks * 32 + quad * 8);
#pragma unroll
        for (int s = 0; s < 2; ++s)
          accS[s][n] = __builtin_amdgcn_mfma_f32_16x16x32_bf16(kf, qf[s][ks], accS[s][n], 0, 0, 0);
      }
    }
    __builtin_amdgcn_s_setprio(0);
  };
  auto expp = [&]() {   // accS -> pP (f16 pairs); no rsum adds (MFMA handles it)
#pragma unroll
    for (int s = 0; s < 2; ++s)
#pragma unroll
      for (int n = 0; n < 4; ++n) {
        float e0 = __builtin_amdgcn_exp2f(accS[s][n][0]);
        float e1 = __builtin_amdgcn_exp2f(accS[s][n][1]);
        float e2 = __builtin_amdgcn_exp2f(accS[s][n][2]);
        float e3 = __builtin_amdgcn_exp2f(accS[s][n][3]);
        f16x2 lo = __builtin_bit_cast(f16x2, __builtin_amdgcn_cvt_pkrtz(e0, e1));
        f16x2 hi = __builtin_bit_cast(f16x2, __builtin_amdgcn_cvt_pkrtz(e2, e3));
        pP[s][n] = f16x4{lo[0], lo[1], hi[0], hi[1]};
      }
  };
  auto pv = [&](int bi) {   // K=32 full-rate f16 MFMA + ones-row rsum
    __builtin_amdgcn_s_setprio(1);
#pragma unroll
    for (int kk = 0; kk < 2; ++kk) {
      union { f16x4 h[2]; f16x8 v8; } u0, u1;
      u0.h[0] = pP[0][2 * kk]; u0.h[1] = pP[0][2 * kk + 1];
      u1.h[0] = pP[1][2 * kk]; u1.h[1] = pP[1][2 * kk + 1];
      accR[0] = __builtin_amdgcn_mfma_f32_16x16x32_f16(vones, u0.v8, accR[0], 0, 0, 0);
      accR[1] = __builtin_amdgcn_mfma_f32_16x16x32_f16(vones, u1.v8, accR[1], 0, 0, 0);
#pragma unroll
      for (int n2 = 0; n2 < 4; ++n2) {
        f16x8 vA = *(const f16x8*)(Vsh[bi] + (n2 * 16 + l15) * 72 + kk * 32 + quad * 8);
        accO[n2][0] = __builtin_amdgcn_mfma_f32_16x16x32_f16(vA, u0.v8, accO[n2][0], 0, 0, 0);
        accO[n2][1] = __builtin_amdgcn_mfma_f32_16x16x32_f16(vA, u1.v8, accO[n2][1], 0, 0, 0);
      }
    }
    __builtin_amdgcn_s_setprio(0);
  };

  // prologue
  ldregs(0);
  wlds(0);
  __syncthreads();
  if (ntiles > 1) ldregs(1);
  qkt(0);
  expp();

  int b0 = 0, b1 = 1;
  for (int t = 0; t < ntiles - 1; ++t) {
    wlds(b1);                     // stage tile t+1 (regs loaded at iter t-1)
    __syncthreads();              // writes visible; 3-ring guards reuse
    if (t + 2 < ntiles) ldregs(t + 2);
    qkt(b1);                      // accS(t+1)  [MFMA]
    pv(b0);                       // PV(t) w/ pP [MFMA]  - independent of accS
    expp();                       // exp(t+1) -> pP [VALU] - overlaps PV issue
    b0 = b1; b1 = (b1 == 2) ? 0 : b1 + 1;
  }
  pv(b0);                         // PV(ntiles-1)

  float rsum[2] = {accR[0][0], accR[1][0]};   // all lanes hold their q's full sum

  if (lsplit) {
    const int slot = (part * BATCH + b) * NH + h;
    const size_t ob = (size_t)slot * TSEQ * HD;
#pragma unroll
    for (int s = 0; s < 2; ++s) {
      const int t = q0 + s * 16 + l15;
#pragma unroll
      for (int n2 = 0; n2 < 4; ++n2) {
        const int d0 = n2 * 16 + quad * 4;
        unsigned short o[4];
#pragma unroll
        for (int r = 0; r < 4; ++r) o[r] = f2bf(accO[n2][s][r]);
        *(s16x4*)(Opart + ob + (size_t)t * HD + d0) = *(const s16x4*)o;
      }
    }
    if (quad == 0) {
      const size_t rb = (size_t)slot * TSEQ;
#pragma unroll
      for (int s = 0; s < 2; ++s)
        rsumP[rb + q0 + s * 16 + l15] = rsum[s];
    }
  } else {
#pragma unroll
    for (int s = 0; s < 2; ++s) {
      const int t = q0 + s * 16 + l15;
      const float inv = 1.f / rsum[s];
#pragma unroll
      for (int n2 = 0; n2 < 4; ++n2) {
        const int d0 = n2 * 16 + quad * 4;
        unsigned short o[4];
#pragma unroll
        for (int r = 0; r < 4; ++r) o[r] = f2bf(accO[n2][s][r] * inv);
        *(s16x4*)(ctx + ((size_t)(b * TSEQ + t)) * HID + h * HD + d0) = *(const s16x4*)o;
      }
    }
  }
}

// ---------------- combine K-split parts (unused at lsplit=0; kept for fallback) ----------------
__global__ __launch_bounds__(256) void combine_k(
    const unsigned short* __restrict__ Opart, const float* __restrict__ rsumP,
    unsigned short* __restrict__ ctx, int nparts) {
  const int gtid = blockIdx.x * 256 + threadIdx.x;  // 524288 total
  const int d = (gtid & 7) * 8;
  const int rem = gtid >> 3;
  const int t = rem & 2047;
  const int bh = rem >> 11;          // b*NH + h  (0..31)
  float acc[8] = {0, 0, 0, 0, 0, 0, 0, 0};
  float rs = 0.f;
  for (int p = 0; p < nparts; ++p) {
    const int slot = p * 32 + bh;
    s16x8 a = *(const s16x8*)(Opart + ((size_t)slot * TSEQ + t) * HD + d);
#pragma unroll
    for (int j = 0; j < 8; ++j) acc[j] += bf2f(((const unsigned short*)&a)[j]);
    rs += rsumP[(size_t)slot * TSEQ + t];
  }
  const float inv = 1.f / rs;
  unsigned short o[8];
#pragma unroll
  for (int j = 0; j < 8; ++j) o[j] = f2bf(acc[j] * inv);
  const int b = bh >> 4, h = bh & 15;
  *(s16x8*)(ctx + ((size_t)(b * TSEQ + t)) * HID + h * HD + d) = *(const s16x8*)o;
}

// ---------------- In-place LayerNorm over rows of 1024 ----------------
__global__ __launch_bounds__(256) void ln_k(float* __restrict__ io,
                                            const float* __restrict__ gamma,
                                            const float* __restrict__ beta) {
  const int row = blockIdx.x, tid = threadIdx.x;
  float x[4]; float s = 0.f, s2 = 0.f;
#pragma unroll
  for (int i = 0; i < 4; ++i) {
    x[i] = io[(size_t)row * HID + tid + i * 256];
    s += x[i]; s2 += x[i] * x[i];
  }
#pragma unroll
  for (int off = 1; off < 64; off <<= 1) {
    s  += __shfl_xor(s, off, 64);
    s2 += __shfl_xor(s2, off, 64);
  }
  __shared__ float red[8];
  const int wave = tid >> 6;
  if ((tid & 63) == 0) { red[wave] = s; red[wave + 4] = s2; }
  __syncthreads();
  s  = red[0] + red[1] + red[2] + red[3];
  s2 = red[4] + red[5] + red[6] + red[7];
  const float mean = s * (1.f / HID);
  const float var  = s2 * (1.f / HID) - mean * mean;
  const float rstd = rsqrtf(var + 1e-6f);
#pragma unroll
  for (int i = 0; i < 4; ++i) {
    const int col = tid + i * 256;
    io[(size_t)row * HID + col] = (x[i] - mean) * rstd * gamma[col] + beta[col];
  }
}

extern "C" void kernel_launch(void* const* d_in, const int* in_sizes, int n_in,
                              void* d_out, int out_size, void* d_ws, size_t ws_size,
                              hipStream_t stream) {
  const float* h    = (const float*)d_in[0];
  const float* Wq   = (const float*)d_in[1];
  const float* bq   = (const float*)d_in[2];
  const float* Wk   = (const float*)d_in[3];
  const float* bk   = (const float*)d_in[4];
  const float* Wv   = (const float*)d_in[5];
  const float* bv   = (const float*)d_in[6];
  const float* Wo   = (const float*)d_in[7];
  const float* bo   = (const float*)d_in[8];
  const float* gamma = (const float*)d_in[9];
  const float* beta  = (const float*)d_in[10];
  float* out = (float*)d_out;

  unsigned short* hb   = (unsigned short*)d_ws;   // bf16 h; dead after gemm_qkv -> reused as ctx
  unsigned short* wqb  = hb  + 4194304;           // 4 weights contiguous (Wq|Wk|Wv|Wo)
  unsigned short* wkb  = wqb + 1048576;
  unsigned short* wvb  = wkb + 1048576;
  unsigned short* wob  = wvb + 1048576;
  unsigned short* qb   = wob + 1048576;           // bf16 [B,NH,T,D]
  unsigned short* kb   = qb  + 4194304;
  unsigned short* vtf  = kb  + 4194304;           // f16 [B,NH,D,T], written by gemm_qkv directly
  unsigned short* Opart = vtf + 4194304;          // (unused at lsplit=0)
  unsigned short* ctxb = hb;                      // ctx aliases dead hb
  float* rsumP = (float*)(Opart + 4194304);       // (unused at lsplit=0)

  // lsplit=0: 512 attn blocks = exactly 2/CU, f32 O accumulation, no combine pass.
  cast_all_k<<<8192, 256, 0, stream>>>(h, Wq, Wk, Wv, Wo, hb, wqb);
  gemm_qkv<<<dim3(16, 32), 256, 0, stream>>>(hb, wqb, bq, bk, bv, qb, kb, vtf);
  attn_k<<<dim3(TSEQ / 128, NH, BATCH), 256, 0, stream>>>(
      qb, kb, vtf, ctxb, Opart, rsumP, 0, 32);
  gemm_out<<<dim3(16, 32), 256, 0, stream>>>(ctxb, wob, bo, h, out);
  ln_k<<<4096, 256, 0, stream>>>(out, gamma, beta);
}